// Round 1
// baseline (690.254 us; speedup 1.0000x reference)
//
#include <hip/hip_runtime.h>
#include <math.h>

#define BB 4
#define NN 8000
#define FIN 256
#define DD 128
#define NB 16
#define BS 500
#define KK 8
#define RPB 32
#define CHUNKS (NN/RPB)   /* 250 */
#define ETOT (BB*NN*KK)   /* 256000 */

// ---------------------------------------------------------------------------
// Kernel 1: point-encoder FFN (256 -> 128 elu -> 128) fused with LSH binning.
// Block = 128 threads handles 32 consecutive rows of one batch.
// Also emits per-chunk histogram + stable local rank (no atomics).
// ---------------------------------------------------------------------------
__global__ __launch_bounds__(128) void k_encode(
    const float* __restrict__ x, const float* __restrict__ w1, const float* __restrict__ b1,
    const float* __restrict__ w2, const float* __restrict__ b2, const float* __restrict__ rot,
    float* __restrict__ pe, int* __restrict__ bin_idx, int* __restrict__ localrank,
    int* __restrict__ chunkhist)
{
  __shared__ float xs[RPB*FIN];      // 32 KB
  __shared__ float hs[RPB*DD];       // 16 KB
  __shared__ float ps[RPB*129];      // 16.5 KB (padded)
  __shared__ float ms[RPB*9];
  __shared__ int   bl[RPB];
  const int t = threadIdx.x;
  const int blk = blockIdx.x;
  const int b = blk / CHUNKS;
  const int chunk = blk % CHUNKS;
  const int row0 = chunk * RPB;

  const float4* xg4 = (const float4*)(x + ((size_t)b*NN + row0)*FIN);
  float4* xs4 = (float4*)xs;
  #pragma unroll
  for (int i=0;i<16;i++) xs4[t + i*128] = xg4[t + i*128];
  __syncthreads();

  float acc[RPB];
  { float bias = b1[t];
    #pragma unroll
    for (int r=0;r<RPB;r++) acc[r]=bias; }
  for (int k=0;k<FIN;k++){
    float w = w1[k*DD + t];
    #pragma unroll
    for (int r=0;r<RPB;r++) acc[r] = fmaf(xs[r*FIN+k], w, acc[r]);
  }
  #pragma unroll
  for (int r=0;r<RPB;r++){ float v=acc[r]; hs[r*DD+t] = v>0.f ? v : expm1f(v); }
  __syncthreads();

  { float bias = b2[t];
    #pragma unroll
    for (int r=0;r<RPB;r++) acc[r]=bias; }
  for (int k=0;k<DD;k++){
    float w = w2[k*DD + t];
    #pragma unroll
    for (int r=0;r<RPB;r++) acc[r] = fmaf(hs[r*DD+k], w, acc[r]);
  }
  #pragma unroll
  for (int r=0;r<RPB;r++){
    float v = acc[r];
    pe[((size_t)b*NN + row0 + r)*DD + t] = v;
    ps[r*129+t] = v;
  }
  __syncthreads();

  // mul = pe @ rot[:, :8] ; thread t -> row t>>2, cols {t&3, (t&3)+4}
  { const int r = t>>2, m0 = t&3;
    float s0=0.f, s1=0.f;
    for (int k=0;k<DD;k++){
      float p = ps[r*129+k];
      s0 = fmaf(p, rot[k*100+m0],   s0);
      s1 = fmaf(p, rot[k*100+m0+4], s1);
    }
    ms[r*9+m0]=s0; ms[r*9+m0+4]=s1; }
  __syncthreads();

  if (t<RPB){
    float best = ms[t*9+0]; int bi=0;
    #pragma unroll
    for (int m=1;m<16;m++){
      float v = (m<8)? ms[t*9+m] : -ms[t*9+(m-8)];
      if (v>best){best=v;bi=m;}           // strict > == argmax first-occurrence
    }
    bl[t]=bi;
    bin_idx[b*NN+row0+t]=bi;
  }
  __syncthreads();
  if (t<RPB){
    int myb=bl[t]; int rk=0;
    for (int r2=0;r2<t;r2++) rk += (bl[r2]==myb) ? 1 : 0;
    localrank[b*NN+row0+t]=rk;
  }
  if (t<NB){
    int cnt=0;
    #pragma unroll
    for (int r2=0;r2<RPB;r2++) cnt += (bl[r2]==t) ? 1 : 0;
    chunkhist[(b*CHUNKS+chunk)*NB + t] = cnt;
  }
}

// ---------------------------------------------------------------------------
// Kernel 2: A = inputs @ edge_w1[0:256], Bv = inputs @ edge_w1[256:512]
// ---------------------------------------------------------------------------
__global__ __launch_bounds__(128) void k_tables(
    const float* __restrict__ x, const float* __restrict__ ew1,
    float* __restrict__ A, float* __restrict__ Bv)
{
  __shared__ float xs[RPB*FIN];
  const int t=threadIdx.x, blk=blockIdx.x;
  const int b=blk/CHUNKS, chunk=blk%CHUNKS, row0=chunk*RPB;
  const float4* xg4=(const float4*)(x+((size_t)b*NN+row0)*FIN);
  float4* xs4=(float4*)xs;
  #pragma unroll
  for (int i=0;i<16;i++) xs4[t+i*128]=xg4[t+i*128];
  __syncthreads();
  float aA[RPB], aB[RPB];
  #pragma unroll
  for (int r=0;r<RPB;r++){aA[r]=0.f;aB[r]=0.f;}
  for (int k=0;k<FIN;k++){
    float wa=ew1[k*DD+t], wb=ew1[(FIN+k)*DD+t];
    #pragma unroll
    for (int r=0;r<RPB;r++){
      float xv=xs[r*FIN+k];
      aA[r]=fmaf(xv,wa,aA[r]); aB[r]=fmaf(xv,wb,aB[r]);
    }
  }
  #pragma unroll
  for (int r=0;r<RPB;r++){
    A [((size_t)b*NN+row0+r)*DD+t]=aA[r];
    Bv[((size_t)b*NN+row0+r)*DD+t]=aB[r];
  }
}

// ---------------------------------------------------------------------------
// Kernel 3: per-batch scan of chunk histograms -> per-chunk/bin base offsets
// ---------------------------------------------------------------------------
__global__ void k_scan(const int* __restrict__ chunkhist, int* __restrict__ cbase){
  const int b=blockIdx.x, t=threadIdx.x;
  __shared__ int tot[NB], start[NB];
  if (t<NB){
    int s=0;
    for (int c=0;c<CHUNKS;c++) s+=chunkhist[(b*CHUNKS+c)*NB+t];
    tot[t]=s;
  }
  __syncthreads();
  if (t==0){
    int run=0;
    for (int m=0;m<NB;m++){ start[m]=run; run+=tot[m]; }
  }
  __syncthreads();
  if (t<NB){
    int run=start[t];
    for (int c=0;c<CHUNKS;c++){
      cbase[(b*CHUNKS+c)*NB+t]=run;
      run+=chunkhist[(b*CHUNKS+c)*NB+t];
    }
  }
}

// ---------------------------------------------------------------------------
// Kernel 4: stable scatter -> bins_split (permutation) + float copy to d_out
// ---------------------------------------------------------------------------
__global__ __launch_bounds__(256) void k_scatter(
    const int* __restrict__ bin_idx, const int* __restrict__ localrank,
    const int* __restrict__ cbase, int* __restrict__ bs, float* __restrict__ out_bins)
{
  int gi=blockIdx.x*256+threadIdx.x;
  if (gi>=BB*NN) return;
  int b=gi/NN, row=gi%NN, chunk=row/RPB;
  int bi=bin_idx[gi];
  int pos=cbase[(b*CHUNKS+chunk)*NB+bi]+localrank[gi];
  bs[b*NN+pos]=row;
  out_bins[b*NN+pos]=(float)row;
}

// ---------------------------------------------------------------------------
// Kernel 5: per (batch, bin, row-tile) pairwise gaussian kernel + top-8,
// dst-sorted, writes indices (as floats) + edge (dst,val) scratch.
// ---------------------------------------------------------------------------
__global__ __launch_bounds__(256) void k_nn(
    const float* __restrict__ pe, const int* __restrict__ bs,
    float* __restrict__ out_idx, int* __restrict__ e_dst, float* __restrict__ e_val)
{
  __shared__ float RT[64*129];   // 33 KB
  __shared__ float CT[64*129];   // 33 KB
  __shared__ float DM[64*65];    // 16.6 KB
  __shared__ float na_r[64];
  __shared__ float na_c[64];
  __shared__ int   bsl[BS];
  const int t=threadIdx.x;
  const int blk=blockIdx.x;                 // b*128 + bin*8 + rt
  const int rt=blk&7, bin=(blk>>3)&15, b=blk>>7;

  for (int i=t;i<BS;i+=256) bsl[i]=bs[b*NN + bin*BS + i];
  __syncthreads();

  const int r0=rt*64;
  const int nr=min(64, BS-r0);              // 64 or 52
  { const int lr=t>>5, c4=t&31;
    #pragma unroll
    for (int pass=0;pass<8;pass++){
      int r=pass*8+lr;
      float vx=0.f,vy=0.f,vz=0.f,vw=0.f;
      if (r<nr){
        const float4 v=*(const float4*)(pe + ((size_t)b*NN + bsl[r0+r])*DD + c4*4);
        vx=v.x;vy=v.y;vz=v.z;vw=v.w;
      }
      float* d=&RT[r*129 + c4*4];
      d[0]=vx;d[1]=vy;d[2]=vz;d[3]=vw;
    } }
  __syncthreads();
  if (t<64){
    float s=0.f;
    for (int k2=0;k2<DD;k2++){ float p=RT[t*129+k2]; s=fmaf(p,p,s); }
    na_r[t]=s;
  }

  float tv[KK]; int ti[KK];
  #pragma unroll
  for (int i=0;i<KK;i++){tv[i]=-1e30f; ti[i]=0;}
  const int tr_=t>>4, tc_=t&15;

  for (int ct=0; ct<8; ++ct){
    const int c0=ct*64;
    const int nc=min(64, BS-c0);
    { const int lr=t>>5, c4=t&31;
      #pragma unroll
      for (int pass=0;pass<8;pass++){
        int c=pass*8+lr;
        float vx=0.f,vy=0.f,vz=0.f,vw=0.f;
        if (c<nc){
          const float4 v=*(const float4*)(pe + ((size_t)b*NN + bsl[c0+c])*DD + c4*4);
          vx=v.x;vy=v.y;vz=v.z;vw=v.w;
        }
        float* d=&CT[c*129 + c4*4];
        d[0]=vx;d[1]=vy;d[2]=vz;d[3]=vw;
      } }
    __syncthreads();
    if (t<64){
      float s=0.f;
      for (int k2=0;k2<DD;k2++){ float p=CT[t*129+k2]; s=fmaf(p,p,s); }
      na_c[t]=s;
    }
    __syncthreads();

    float accm[4][4];
    #pragma unroll
    for (int i=0;i<4;i++){
      #pragma unroll
      for (int j=0;j<4;j++) accm[i][j]=0.f; }
    for (int k2=0;k2<DD;k2++){
      float av[4], bv[4];
      #pragma unroll
      for (int i=0;i<4;i++) av[i]=RT[(tr_*4+i)*129+k2];
      #pragma unroll
      for (int j=0;j<4;j++) bv[j]=CT[(tc_*4+j)*129+k2];
      #pragma unroll
      for (int i=0;i<4;i++){
        #pragma unroll
        for (int j=0;j<4;j++) accm[i][j]=fmaf(av[i],bv[j],accm[i][j]); }
    }
    #pragma unroll
    for (int i=0;i<4;i++){
      int r=tr_*4+i;
      #pragma unroll
      for (int j=0;j<4;j++){
        int c=tc_*4+j;
        float t1=na_r[r]-2.f*accm[i][j];
        float d2v=t1+na_c[c];
        float dm=(r<nr && c<nc)? expf(-0.1f*sqrtf(fmaxf(d2v,1e-6f))) : -1e30f;
        DM[r*65+c]=dm;
      } }
    __syncthreads();

    if (t<nr){
      for (int c=0;c<nc;c++){
        float v=DM[t*65+c];
        if (v>tv[KK-1]){                    // strict > : lax.top_k tie semantics
          tv[KK-1]=v; ti[KK-1]=c0+c;
          #pragma unroll
          for (int q=KK-1;q>0;q--){
            if (tv[q]>tv[q-1]){
              float tmpv=tv[q];tv[q]=tv[q-1];tv[q-1]=tmpv;
              int   tmpi=ti[q];ti[q]=ti[q-1];ti[q-1]=tmpi;
            }
          }
        }
      }
    }
    __syncthreads();
  }

  if (t<nr){
    const int src=bsl[r0+t];
    int dsts[KK]; float vv[KK];
    #pragma unroll
    for (int k2=0;k2<KK;k2++){ dsts[k2]=bsl[ti[k2]]; vv[k2]=tv[k2]; }
    // Batcher odd-even mergesort (19 comparators), sort by dst ascending
    #define CSWAP(a_,b_) { if (dsts[a_]>dsts[b_]){ int td=dsts[a_];dsts[a_]=dsts[b_];dsts[b_]=td; float tf=vv[a_];vv[a_]=vv[b_];vv[b_]=tf; } }
    CSWAP(0,1) CSWAP(2,3) CSWAP(4,5) CSWAP(6,7)
    CSWAP(0,2) CSWAP(1,3) CSWAP(4,6) CSWAP(5,7)
    CSWAP(1,2) CSWAP(5,6)
    CSWAP(0,4) CSWAP(1,5) CSWAP(2,6) CSWAP(3,7)
    CSWAP(2,4) CSWAP(3,5)
    CSWAP(1,2) CSWAP(3,4) CSWAP(5,6)
    #undef CSWAP
    size_t e0=((size_t)b*NN + src)*KK;
    #pragma unroll
    for (int k2=0;k2<KK;k2++){
      out_idx[3*(e0+k2)+0]=(float)b;
      out_idx[3*(e0+k2)+1]=(float)src;
      out_idx[3*(e0+k2)+2]=(float)dsts[k2];
      e_dst[e0+k2]=dsts[k2];
      e_val[e0+k2]=vv[k2];
    }
  }
}

// ---------------------------------------------------------------------------
// Kernel 6: edge MLP. One wave per (b,src) group of 8 edges.
// h = elu(A[src] + Bv[dst] + val*w1c + b1); out = sigmoid(h . W2 + b2)
// ---------------------------------------------------------------------------
__global__ __launch_bounds__(256) void k_edge(
    const float* __restrict__ A, const float* __restrict__ Bv,
    const float* __restrict__ ew1, const float* __restrict__ eb1,
    const float* __restrict__ ew2, const float* __restrict__ eb2,
    const int* __restrict__ e_dst, const float* __restrict__ e_val,
    float* __restrict__ out_vals)
{
  const int wid = (int)((blockIdx.x*256u+threadIdx.x)>>6);
  const int lane = threadIdx.x&63;
  if (wid >= BB*NN) return;
  const int b = wid / NN;
  const float2 a2  = *(const float2*)(A   + (size_t)wid*DD + lane*2);
  const float2 wc  = *(const float2*)(ew1 + (size_t)512*DD + lane*2);
  const float2 bb1 = *(const float2*)(eb1 + lane*2);
  const float2 w2v = *(const float2*)(ew2 + lane*2);
  const float  b2s = eb2[0];
  const size_t e0 = (size_t)wid*KK;
  #pragma unroll
  for (int k=0;k<KK;k++){
    int dst = e_dst[e0+k];
    float val = e_val[e0+k];
    const float2 bv = *(const float2*)(Bv + ((size_t)b*NN+dst)*DD + lane*2);
    float h0 = a2.x + bv.x + val*wc.x + bb1.x;  h0 = h0>0.f ? h0 : expm1f(h0);
    float h1 = a2.y + bv.y + val*wc.y + bb1.y;  h1 = h1>0.f ? h1 : expm1f(h1);
    float s = h0*w2v.x + h1*w2v.y;
    #pragma unroll
    for (int off=32; off; off>>=1) s += __shfl_xor(s, off);
    if (lane==k) out_vals[e0+k] = 1.f/(1.f+expf(-(s+b2s)));
  }
}

// ---------------------------------------------------------------------------
extern "C" void kernel_launch(void* const* d_in, const int* in_sizes, int n_in,
                              void* d_out, int out_size, void* d_ws, size_t ws_size,
                              hipStream_t stream)
{
  const float* x    = (const float*)d_in[0];
  const float* ew1v = (const float*)d_in[1]; // enc_w1
  const float* eb1v = (const float*)d_in[2]; // enc_b1
  const float* ew2v = (const float*)d_in[3]; // enc_w2
  const float* eb2v = (const float*)d_in[4]; // enc_b2
  const float* gw1  = (const float*)d_in[5]; // edge_w1 [513,128]
  const float* gb1  = (const float*)d_in[6]; // edge_b1
  const float* gw2  = (const float*)d_in[7]; // edge_w2 [128,1]
  const float* gb2  = (const float*)d_in[8]; // edge_b2
  const float* rot  = (const float*)d_in[9]; // [128,100]

  char* w = (char*)d_ws;
  float* pe   = (float*)w;  w += (size_t)BB*NN*DD*4;     // 16.38 MB
  float* Atab = (float*)w;  w += (size_t)BB*NN*DD*4;     // 16.38 MB
  float* Btab = (float*)w;  w += (size_t)BB*NN*DD*4;     // 16.38 MB
  int*   bin_idx   = (int*)w; w += (size_t)BB*NN*4;
  int*   localrank = (int*)w; w += (size_t)BB*NN*4;
  int*   chunkhist = (int*)w; w += (size_t)BB*CHUNKS*NB*4;
  int*   cbase     = (int*)w; w += (size_t)BB*CHUNKS*NB*4;
  int*   bs        = (int*)w; w += (size_t)BB*NN*4;
  int*   e_dst     = (int*)w; w += (size_t)ETOT*4;
  float* e_val     = (float*)w; w += (size_t)ETOT*4;

  float* out_idx  = (float*)d_out;                 // 768000
  float* out_vals = out_idx + (size_t)ETOT*3;      // 256000
  float* out_bins = out_vals + ETOT;               // 32000

  k_encode<<<dim3(BB*CHUNKS), dim3(128), 0, stream>>>(
      x, ew1v, eb1v, ew2v, eb2v, rot, pe, bin_idx, localrank, chunkhist);
  k_tables<<<dim3(BB*CHUNKS), dim3(128), 0, stream>>>(x, gw1, Atab, Btab);
  k_scan<<<dim3(BB), dim3(64), 0, stream>>>(chunkhist, cbase);
  k_scatter<<<dim3((BB*NN+255)/256), dim3(256), 0, stream>>>(
      bin_idx, localrank, cbase, bs, out_bins);
  k_nn<<<dim3(BB*NB*8), dim3(256), 0, stream>>>(pe, bs, out_idx, e_dst, e_val);
  k_edge<<<dim3(BB*NN/4), dim3(256), 0, stream>>>(
      Atab, Btab, gw1, gb1, gw2, gb2, e_dst, e_val, out_vals);
}

// Round 2
// 585.244 us; speedup vs baseline: 1.1794x; 1.1794x over previous
//
#include <hip/hip_runtime.h>
#include <math.h>

#define BB 4
#define NN 8000
#define FIN 256
#define DD 128
#define NB 16
#define BS 500
#define KK 8
#define RPB 32
#define CHUNKS (NN/RPB)   /* 250 */
#define ETOT (BB*NN*KK)   /* 256000 */

// ---------------------------------------------------------------------------
// Kernel 1: point-encoder FFN (256 -> 128 elu -> 128) fused with LSH binning.
// ---------------------------------------------------------------------------
__global__ __launch_bounds__(128) void k_encode(
    const float* __restrict__ x, const float* __restrict__ w1, const float* __restrict__ b1,
    const float* __restrict__ w2, const float* __restrict__ b2, const float* __restrict__ rot,
    float* __restrict__ pe, int* __restrict__ bin_idx, int* __restrict__ localrank,
    int* __restrict__ chunkhist)
{
  __shared__ float xs[RPB*FIN];      // 32 KB
  __shared__ float hs[RPB*DD];       // 16 KB
  __shared__ float ps[RPB*129];      // 16.5 KB (padded)
  __shared__ float ms[RPB*9];
  __shared__ int   bl[RPB];
  const int t = threadIdx.x;
  const int blk = blockIdx.x;
  const int b = blk / CHUNKS;
  const int chunk = blk % CHUNKS;
  const int row0 = chunk * RPB;

  const float4* xg4 = (const float4*)(x + ((size_t)b*NN + row0)*FIN);
  float4* xs4 = (float4*)xs;
  #pragma unroll
  for (int i=0;i<16;i++) xs4[t + i*128] = xg4[t + i*128];
  __syncthreads();

  float acc[RPB];
  { float bias = b1[t];
    #pragma unroll
    for (int r=0;r<RPB;r++) acc[r]=bias; }
  for (int k=0;k<FIN;k++){
    float w = w1[k*DD + t];
    #pragma unroll
    for (int r=0;r<RPB;r++) acc[r] = fmaf(xs[r*FIN+k], w, acc[r]);
  }
  #pragma unroll
  for (int r=0;r<RPB;r++){ float v=acc[r]; hs[r*DD+t] = v>0.f ? v : expm1f(v); }
  __syncthreads();

  { float bias = b2[t];
    #pragma unroll
    for (int r=0;r<RPB;r++) acc[r]=bias; }
  for (int k=0;k<DD;k++){
    float w = w2[k*DD + t];
    #pragma unroll
    for (int r=0;r<RPB;r++) acc[r] = fmaf(hs[r*DD+k], w, acc[r]);
  }
  #pragma unroll
  for (int r=0;r<RPB;r++){
    float v = acc[r];
    pe[((size_t)b*NN + row0 + r)*DD + t] = v;
    ps[r*129+t] = v;
  }
  __syncthreads();

  { const int r = t>>2, m0 = t&3;
    float s0=0.f, s1=0.f;
    for (int k=0;k<DD;k++){
      float p = ps[r*129+k];
      s0 = fmaf(p, rot[k*100+m0],   s0);
      s1 = fmaf(p, rot[k*100+m0+4], s1);
    }
    ms[r*9+m0]=s0; ms[r*9+m0+4]=s1; }
  __syncthreads();

  if (t<RPB){
    float best = ms[t*9+0]; int bi=0;
    #pragma unroll
    for (int m=1;m<16;m++){
      float v = (m<8)? ms[t*9+m] : -ms[t*9+(m-8)];
      if (v>best){best=v;bi=m;}
    }
    bl[t]=bi;
    bin_idx[b*NN+row0+t]=bi;
  }
  __syncthreads();
  if (t<RPB){
    int myb=bl[t]; int rk=0;
    for (int r2=0;r2<t;r2++) rk += (bl[r2]==myb) ? 1 : 0;
    localrank[b*NN+row0+t]=rk;
  }
  if (t<NB){
    int cnt=0;
    #pragma unroll
    for (int r2=0;r2<RPB;r2++) cnt += (bl[r2]==t) ? 1 : 0;
    chunkhist[(b*CHUNKS+chunk)*NB + t] = cnt;
  }
}

// ---------------------------------------------------------------------------
// Kernel 2: A = inputs @ edge_w1[0:256], Bv = inputs @ edge_w1[256:512]
// ---------------------------------------------------------------------------
__global__ __launch_bounds__(128) void k_tables(
    const float* __restrict__ x, const float* __restrict__ ew1,
    float* __restrict__ A, float* __restrict__ Bv)
{
  __shared__ float xs[RPB*FIN];
  const int t=threadIdx.x, blk=blockIdx.x;
  const int b=blk/CHUNKS, chunk=blk%CHUNKS, row0=chunk*RPB;
  const float4* xg4=(const float4*)(x+((size_t)b*NN+row0)*FIN);
  float4* xs4=(float4*)xs;
  #pragma unroll
  for (int i=0;i<16;i++) xs4[t+i*128]=xg4[t+i*128];
  __syncthreads();
  float aA[RPB], aB[RPB];
  #pragma unroll
  for (int r=0;r<RPB;r++){aA[r]=0.f;aB[r]=0.f;}
  for (int k=0;k<FIN;k++){
    float wa=ew1[k*DD+t], wb=ew1[(FIN+k)*DD+t];
    #pragma unroll
    for (int r=0;r<RPB;r++){
      float xv=xs[r*FIN+k];
      aA[r]=fmaf(xv,wa,aA[r]); aB[r]=fmaf(xv,wb,aB[r]);
    }
  }
  #pragma unroll
  for (int r=0;r<RPB;r++){
    A [((size_t)b*NN+row0+r)*DD+t]=aA[r];
    Bv[((size_t)b*NN+row0+r)*DD+t]=aB[r];
  }
}

// ---------------------------------------------------------------------------
// Kernel 3 (fused scan+scatter): per-batch scan of chunk histograms then
// stable scatter -> bins_split permutation + float copy to d_out.
// ---------------------------------------------------------------------------
__global__ __launch_bounds__(256) void k_scan_scatter(
    const int* __restrict__ bin_idx, const int* __restrict__ localrank,
    const int* __restrict__ chunkhist, int* __restrict__ bs, float* __restrict__ out_bins)
{
  const int b=blockIdx.x, t=threadIdx.x;
  __shared__ int cbase_s[CHUNKS*NB];    // 16 KB
  __shared__ int tot[NB], start[NB];
  if (t<NB){
    int s=0;
    for (int c=0;c<CHUNKS;c++) s+=chunkhist[(b*CHUNKS+c)*NB+t];
    tot[t]=s;
  }
  __syncthreads();
  if (t==0){
    int run=0;
    for (int m=0;m<NB;m++){ start[m]=run; run+=tot[m]; }
  }
  __syncthreads();
  if (t<NB){
    int run=start[t];
    for (int c=0;c<CHUNKS;c++){
      cbase_s[c*NB+t]=run;
      run+=chunkhist[(b*CHUNKS+c)*NB+t];
    }
  }
  __syncthreads();
  for (int row=t; row<NN; row+=256){
    int gi=b*NN+row;
    int chunk=row>>5;                    // RPB==32
    int bi=bin_idx[gi];
    int pos=cbase_s[chunk*NB+bi]+localrank[gi];
    bs[b*NN+pos]=row;
    out_bins[b*NN+pos]=(float)row;
  }
}

// ---------------------------------------------------------------------------
// Kernel 4: per (batch, bin, 64-row tile) pairwise gaussian kernel + top-8.
// Register-resident per-thread partial top-8 (no DM matrix, no serial scan),
// final tie-aware merge, dst-sort, direct write.
// ---------------------------------------------------------------------------
__global__ __launch_bounds__(256) void k_nn(
    const float* __restrict__ pe, const int* __restrict__ bs,
    float* __restrict__ out_idx, int* __restrict__ e_dst, float* __restrict__ e_val)
{
  __shared__ float RT[64*129];   // 33 KB (row tile / later: merge vals)
  __shared__ float CT[64*129];   // 33 KB (col tile / later: merge idx)
  __shared__ float na_all[512];
  __shared__ int   bsl[BS];
  const int t=threadIdx.x;
  const int blk=blockIdx.x;                 // b*128 + bin*8 + rt
  const int rt=blk&7, bin=(blk>>3)&15, b=blk>>7;

  for (int i=t;i<BS;i+=256) bsl[i]=bs[b*NN + bin*BS + i];
  __syncthreads();

  // squared norms for all 500 bin members (sequential-order accumulation,
  // identical rounding path to the previously-verified version)
  for (int i=t;i<BS;i+=256){
    const float* pr = pe + ((size_t)b*NN + bsl[i])*DD;
    float s=0.f;
    for (int k=0;k<DD;k+=4){
      float4 v=*(const float4*)(pr+k);
      s=fmaf(v.x,v.x,s); s=fmaf(v.y,v.y,s); s=fmaf(v.z,v.z,s); s=fmaf(v.w,v.w,s);
    }
    na_all[i]=s;
  }

  const int r0=rt*64;
  const int nr=min(64, BS-r0);              // 64 or 52
  { const int lr=t>>5, c4=t&31;
    #pragma unroll
    for (int pass=0;pass<8;pass++){
      int r=pass*8+lr;
      float4 v=make_float4(0.f,0.f,0.f,0.f);
      if (r<nr) v=*(const float4*)(pe + ((size_t)b*NN + bsl[r0+r])*DD + c4*4);
      float* d=&RT[r*129 + c4*4];
      d[0]=v.x;d[1]=v.y;d[2]=v.z;d[3]=v.w;
    } }

  // per-thread top-8 lists for 4 owned rows over this thread's column slice
  float tv[4][8]; int tix[4][8];
  #pragma unroll
  for (int i=0;i<4;i++){
    #pragma unroll
    for (int s=0;s<8;s++){ tv[i][s]=-1e30f; tix[i][s]=0; } }

  const int tr_=t>>4, tc_=t&15;

  for (int ct=0; ct<8; ++ct){
    __syncthreads();                        // prev-iter readers done (ct=0: RT/na visible gate next)
    const int c0=ct*64;
    const int nc=min(64, BS-c0);
    { const int lr=t>>5, c4=t&31;
      #pragma unroll
      for (int pass=0;pass<8;pass++){
        int c=pass*8+lr;
        float4 v=make_float4(0.f,0.f,0.f,0.f);
        if (c<nc) v=*(const float4*)(pe + ((size_t)b*NN + bsl[c0+c])*DD + c4*4);
        float* d=&CT[c*129 + c4*4];
        d[0]=v.x;d[1]=v.y;d[2]=v.z;d[3]=v.w;
      } }
    __syncthreads();

    float accm[4][4];
    #pragma unroll
    for (int i=0;i<4;i++){
      #pragma unroll
      for (int j=0;j<4;j++) accm[i][j]=0.f; }
    for (int k2=0;k2<DD;k2++){
      float av[4], bv[4];
      #pragma unroll
      for (int i=0;i<4;i++) av[i]=RT[(tr_*4+i)*129+k2];
      #pragma unroll
      for (int j=0;j<4;j++) bv[j]=CT[(tc_*4+j)*129+k2];
      #pragma unroll
      for (int i=0;i<4;i++){
        #pragma unroll
        for (int j=0;j<4;j++) accm[i][j]=fmaf(av[i],bv[j],accm[i][j]); }
    }

    float nrow[4], ncol[4];
    #pragma unroll
    for (int i=0;i<4;i++) nrow[i]=na_all[r0+tr_*4+i];
    #pragma unroll
    for (int j=0;j<4;j++) ncol[j]=na_all[c0+tc_*4+j];

    #pragma unroll
    for (int i=0;i<4;i++){
      #pragma unroll
      for (int j=0;j<4;j++){
        float t1=nrow[i]-2.f*accm[i][j];     // exact order as verified version
        float d2v=t1+ncol[j];
        float dm=expf(-0.1f*sqrtf(fmaxf(d2v,1e-6f)));
        int c=c0+tc_*4+j;
        if (c<BS && dm>tv[i][7]){            // strict > : lax.top_k tie semantics
          tv[i][7]=dm; tix[i][7]=c;
          #pragma unroll
          for (int q=7;q>0;q--){
            if (tv[i][q]>tv[i][q-1]){
              float tf=tv[i][q];tv[i][q]=tv[i][q-1];tv[i][q-1]=tf;
              int   td=tix[i][q];tix[i][q]=tix[i][q-1];tix[i][q-1]=td;
            }
          }
        }
      }
    }
  }

  // dump partial lists to LDS (reuse RT=vals, CT=idx)
  __syncthreads();
  #pragma unroll
  for (int i=0;i<4;i++){
    const int row=tr_*4+i;
    #pragma unroll
    for (int s=0;s<8;s++){
      RT[row*129 + tc_*8 + s]=tv[i][s];
      CT[row*129 + tc_*8 + s]=__int_as_float(tix[i][s]);
    }
  }
  __syncthreads();

  if (t<nr){
    // merge 16 partial top-8s; total order (val desc, colpos asc) == top_k
    float mv[8]; int mi[8];
    #pragma unroll
    for (int s=0;s<8;s++){ mv[s]=-1e30f; mi[s]=0; }
    for (int p=0;p<128;p++){
      float v=RT[t*129+p]; int c=__float_as_int(CT[t*129+p]);
      if (v>mv[7] || (v==mv[7] && c<mi[7])){
        mv[7]=v; mi[7]=c;
        #pragma unroll
        for (int q=7;q>0;q--){
          bool sw=(mv[q]>mv[q-1]) || (mv[q]==mv[q-1] && mi[q]<mi[q-1]);
          if (sw){
            float tf=mv[q];mv[q]=mv[q-1];mv[q-1]=tf;
            int   td=mi[q];mi[q]=mi[q-1];mi[q-1]=td;
          }
        }
      }
    }
    const int src=bsl[r0+t];
    int dsts[KK]; float vv[KK];
    #pragma unroll
    for (int k2=0;k2<KK;k2++){ dsts[k2]=bsl[mi[k2]]; vv[k2]=mv[k2]; }
    // Batcher odd-even mergesort (19 comparators), sort by dst ascending
    #define CSWAP(a_,b_) { if (dsts[a_]>dsts[b_]){ int td=dsts[a_];dsts[a_]=dsts[b_];dsts[b_]=td; float tf=vv[a_];vv[a_]=vv[b_];vv[b_]=tf; } }
    CSWAP(0,1) CSWAP(2,3) CSWAP(4,5) CSWAP(6,7)
    CSWAP(0,2) CSWAP(1,3) CSWAP(4,6) CSWAP(5,7)
    CSWAP(1,2) CSWAP(5,6)
    CSWAP(0,4) CSWAP(1,5) CSWAP(2,6) CSWAP(3,7)
    CSWAP(2,4) CSWAP(3,5)
    CSWAP(1,2) CSWAP(3,4) CSWAP(5,6)
    #undef CSWAP
    size_t e0=((size_t)b*NN + src)*KK;
    #pragma unroll
    for (int k2=0;k2<KK;k2++){
      out_idx[3*(e0+k2)+0]=(float)b;
      out_idx[3*(e0+k2)+1]=(float)src;
      out_idx[3*(e0+k2)+2]=(float)dsts[k2];
      e_dst[e0+k2]=dsts[k2];
      e_val[e0+k2]=vv[k2];
    }
  }
}

// ---------------------------------------------------------------------------
// Kernel 5: edge MLP. One wave per (b,src) group of 8 edges.
// ---------------------------------------------------------------------------
__global__ __launch_bounds__(256) void k_edge(
    const float* __restrict__ A, const float* __restrict__ Bv,
    const float* __restrict__ ew1, const float* __restrict__ eb1,
    const float* __restrict__ ew2, const float* __restrict__ eb2,
    const int* __restrict__ e_dst, const float* __restrict__ e_val,
    float* __restrict__ out_vals)
{
  const int wid = (int)((blockIdx.x*256u+threadIdx.x)>>6);
  const int lane = threadIdx.x&63;
  if (wid >= BB*NN) return;
  const int b = wid / NN;
  const float2 a2  = *(const float2*)(A   + (size_t)wid*DD + lane*2);
  const float2 wc  = *(const float2*)(ew1 + (size_t)512*DD + lane*2);
  const float2 bb1 = *(const float2*)(eb1 + lane*2);
  const float2 w2v = *(const float2*)(ew2 + lane*2);
  const float  b2s = eb2[0];
  const size_t e0 = (size_t)wid*KK;
  #pragma unroll
  for (int k=0;k<KK;k++){
    int dst = e_dst[e0+k];
    float val = e_val[e0+k];
    const float2 bv = *(const float2*)(Bv + ((size_t)b*NN+dst)*DD + lane*2);
    float h0 = a2.x + bv.x + val*wc.x + bb1.x;  h0 = h0>0.f ? h0 : expm1f(h0);
    float h1 = a2.y + bv.y + val*wc.y + bb1.y;  h1 = h1>0.f ? h1 : expm1f(h1);
    float s = h0*w2v.x + h1*w2v.y;
    #pragma unroll
    for (int off=32; off; off>>=1) s += __shfl_xor(s, off);
    if (lane==k) out_vals[e0+k] = 1.f/(1.f+expf(-(s+b2s)));
  }
}

// ---------------------------------------------------------------------------
extern "C" void kernel_launch(void* const* d_in, const int* in_sizes, int n_in,
                              void* d_out, int out_size, void* d_ws, size_t ws_size,
                              hipStream_t stream)
{
  const float* x    = (const float*)d_in[0];
  const float* ew1v = (const float*)d_in[1];
  const float* eb1v = (const float*)d_in[2];
  const float* ew2v = (const float*)d_in[3];
  const float* eb2v = (const float*)d_in[4];
  const float* gw1  = (const float*)d_in[5];
  const float* gb1  = (const float*)d_in[6];
  const float* gw2  = (const float*)d_in[7];
  const float* gb2  = (const float*)d_in[8];
  const float* rot  = (const float*)d_in[9];

  char* w = (char*)d_ws;
  float* pe   = (float*)w;  w += (size_t)BB*NN*DD*4;
  float* Atab = (float*)w;  w += (size_t)BB*NN*DD*4;
  float* Btab = (float*)w;  w += (size_t)BB*NN*DD*4;
  int*   bin_idx   = (int*)w; w += (size_t)BB*NN*4;
  int*   localrank = (int*)w; w += (size_t)BB*NN*4;
  int*   chunkhist = (int*)w; w += (size_t)BB*CHUNKS*NB*4;
  int*   bs        = (int*)w; w += (size_t)BB*NN*4;
  int*   e_dst     = (int*)w; w += (size_t)ETOT*4;
  float* e_val     = (float*)w; w += (size_t)ETOT*4;

  float* out_idx  = (float*)d_out;
  float* out_vals = out_idx + (size_t)ETOT*3;
  float* out_bins = out_vals + ETOT;

  k_encode<<<dim3(BB*CHUNKS), dim3(128), 0, stream>>>(
      x, ew1v, eb1v, ew2v, eb2v, rot, pe, bin_idx, localrank, chunkhist);
  k_tables<<<dim3(BB*CHUNKS), dim3(128), 0, stream>>>(x, gw1, Atab, Btab);
  k_scan_scatter<<<dim3(BB), dim3(256), 0, stream>>>(
      bin_idx, localrank, chunkhist, bs, out_bins);
  k_nn<<<dim3(BB*NB*8), dim3(256), 0, stream>>>(pe, bs, out_idx, e_dst, e_val);
  k_edge<<<dim3(BB*NN/4), dim3(256), 0, stream>>>(
      Atab, Btab, gw1, gb1, gw2, gb2, e_dst, e_val, out_vals);
}

// Round 3
// 529.718 us; speedup vs baseline: 1.3031x; 1.1048x over previous
//
#include <hip/hip_runtime.h>
#include <math.h>

#define BB 4
#define NN 8000
#define FIN 256
#define DD 128
#define NB 16
#define BS 500
#define KK 8
#define RPB 32
#define CHUNKS (NN/RPB)   /* 250 */
#define ETOT (BB*NN*KK)   /* 256000 */

// ---------------------------------------------------------------------------
// Kernel 1: point-encoder FFN (256 -> 128 elu -> 128) fused with LSH binning.
// Register-blocked 4x8 GEMM, weights staged in LDS k-tiles, b128 LDS reads.
// Arithmetic bit-identical to previous version (bias-first, k-ascending fmaf).
// ---------------------------------------------------------------------------
__global__ __launch_bounds__(128) void k_encode(
    const float* __restrict__ x, const float* __restrict__ w1, const float* __restrict__ b1,
    const float* __restrict__ w2, const float* __restrict__ b2, const float* __restrict__ rot,
    float* __restrict__ pe, int* __restrict__ bin_idx, int* __restrict__ localrank,
    int* __restrict__ chunkhist)
{
  __shared__ float xs[RPB*260];   // 33.3 KB (row stride 260: 2-way banks, 16B aligned)
  __shared__ float ws[32*132];    // 16.9 KB weight k-tile
  __shared__ float hs[RPB*132];   // 16.9 KB activations; reused as ps
  __shared__ float ms[RPB*9];
  __shared__ int   bl[RPB];
  const int t = threadIdx.x;
  const int b = blockIdx.x / CHUNKS;
  const int chunk = blockIdx.x % CHUNKS;
  const int row0 = chunk * RPB;
  const int ri = t >> 4;          // 0..7  -> rows ri*4..+3
  const int ci = t & 15;          // 0..15 -> cols ci*8..+7

  // stage x rows: 32x256 floats = 2048 float4, coalesced
  { const float4* xg4 = (const float4*)(x + ((size_t)b*NN + row0)*FIN);
    #pragma unroll
    for (int p=0;p<16;p++){
      int idx4 = t + p*128;
      int r = idx4 >> 6, c4 = idx4 & 63;
      *(float4*)&xs[r*260 + c4*4] = xg4[idx4];
    } }

  float acc[4][8];
  #pragma unroll
  for (int i=0;i<4;i++){
    #pragma unroll
    for (int j=0;j<8;j++) acc[i][j] = b1[ci*8+j]; }
  __syncthreads();

  // ---- layer 1: K=256 in 8 tiles of 32 ----
  for (int kt=0; kt<8; ++kt){
    { const float4* wg = (const float4*)(w1 + (size_t)kt*32*DD);
      #pragma unroll
      for (int p=0;p<8;p++){
        int idx4 = t + p*128;
        int k = idx4 >> 5, c4 = idx4 & 31;
        *(float4*)&ws[k*132 + c4*4] = wg[idx4];
      } }
    __syncthreads();
    #pragma unroll
    for (int kc=0; kc<32; kc+=4){
      float4 a4[4];
      #pragma unroll
      for (int i=0;i<4;i++) a4[i] = *(const float4*)&xs[(ri*4+i)*260 + kt*32 + kc];
      #pragma unroll
      for (int kk=0; kk<4; kk++){
        float4 wlo = *(const float4*)&ws[(kc+kk)*132 + ci*8];
        float4 whi = *(const float4*)&ws[(kc+kk)*132 + ci*8 + 4];
        #pragma unroll
        for (int i=0;i<4;i++){
          float av = ((const float*)&a4[i])[kk];
          acc[i][0]=fmaf(av,wlo.x,acc[i][0]); acc[i][1]=fmaf(av,wlo.y,acc[i][1]);
          acc[i][2]=fmaf(av,wlo.z,acc[i][2]); acc[i][3]=fmaf(av,wlo.w,acc[i][3]);
          acc[i][4]=fmaf(av,whi.x,acc[i][4]); acc[i][5]=fmaf(av,whi.y,acc[i][5]);
          acc[i][6]=fmaf(av,whi.z,acc[i][6]); acc[i][7]=fmaf(av,whi.w,acc[i][7]);
        }
      }
    }
    __syncthreads();
  }

  // elu -> hs
  #pragma unroll
  for (int i=0;i<4;i++){
    int r = ri*4+i;
    #pragma unroll
    for (int j=0;j<8;j++){
      float v = acc[i][j];
      hs[r*132 + ci*8 + j] = v>0.f ? v : expm1f(v);
    } }
  __syncthreads();

  // ---- layer 2: K=128 in 4 tiles of 32 ----
  float acc2[4][8];
  #pragma unroll
  for (int i=0;i<4;i++){
    #pragma unroll
    for (int j=0;j<8;j++) acc2[i][j] = b2[ci*8+j]; }
  for (int kt=0; kt<4; ++kt){
    { const float4* wg = (const float4*)(w2 + (size_t)kt*32*DD);
      #pragma unroll
      for (int p=0;p<8;p++){
        int idx4 = t + p*128;
        int k = idx4 >> 5, c4 = idx4 & 31;
        *(float4*)&ws[k*132 + c4*4] = wg[idx4];
      } }
    __syncthreads();
    #pragma unroll
    for (int kc=0; kc<32; kc+=4){
      float4 a4[4];
      #pragma unroll
      for (int i=0;i<4;i++) a4[i] = *(const float4*)&hs[(ri*4+i)*132 + kt*32 + kc];
      #pragma unroll
      for (int kk=0; kk<4; kk++){
        float4 wlo = *(const float4*)&ws[(kc+kk)*132 + ci*8];
        float4 whi = *(const float4*)&ws[(kc+kk)*132 + ci*8 + 4];
        #pragma unroll
        for (int i=0;i<4;i++){
          float av = ((const float*)&a4[i])[kk];
          acc2[i][0]=fmaf(av,wlo.x,acc2[i][0]); acc2[i][1]=fmaf(av,wlo.y,acc2[i][1]);
          acc2[i][2]=fmaf(av,wlo.z,acc2[i][2]); acc2[i][3]=fmaf(av,wlo.w,acc2[i][3]);
          acc2[i][4]=fmaf(av,whi.x,acc2[i][4]); acc2[i][5]=fmaf(av,whi.y,acc2[i][5]);
          acc2[i][6]=fmaf(av,whi.z,acc2[i][6]); acc2[i][7]=fmaf(av,whi.w,acc2[i][7]);
        }
      }
    }
    __syncthreads();
  }

  // write pe + ps (reuse hs buffer; all layer-2 reads are done)
  #pragma unroll
  for (int i=0;i<4;i++){
    int r = ri*4+i;
    float* pg = pe + ((size_t)b*NN + row0 + r)*DD + ci*8;
    #pragma unroll
    for (int j=0;j<8;j+=4){
      float4 v = make_float4(acc2[i][j],acc2[i][j+1],acc2[i][j+2],acc2[i][j+3]);
      *(float4*)(pg + j) = v;
      *(float4*)&hs[r*132 + ci*8 + j] = v;
    } }
  __syncthreads();

  // LSH binning (identical math to verified version; ps stride 129->132)
  { const int r = t>>2, m0 = t&3;
    float s0=0.f, s1=0.f;
    for (int k=0;k<DD;k++){
      float p = hs[r*132+k];
      s0 = fmaf(p, rot[k*100+m0],   s0);
      s1 = fmaf(p, rot[k*100+m0+4], s1);
    }
    ms[r*9+m0]=s0; ms[r*9+m0+4]=s1; }
  __syncthreads();

  if (t<RPB){
    float best = ms[t*9+0]; int bi=0;
    #pragma unroll
    for (int m=1;m<16;m++){
      float v = (m<8)? ms[t*9+m] : -ms[t*9+(m-8)];
      if (v>best){best=v;bi=m;}
    }
    bl[t]=bi;
    bin_idx[b*NN+row0+t]=bi;
  }
  __syncthreads();
  if (t<RPB){
    int myb=bl[t]; int rk=0;
    for (int r2=0;r2<t;r2++) rk += (bl[r2]==myb) ? 1 : 0;
    localrank[b*NN+row0+t]=rk;
  }
  if (t<NB){
    int cnt=0;
    #pragma unroll
    for (int r2=0;r2<RPB;r2++) cnt += (bl[r2]==t) ? 1 : 0;
    chunkhist[(b*CHUNKS+chunk)*NB + t] = cnt;
  }
}

// ---------------------------------------------------------------------------
// Kernel 2: A = inputs @ edge_w1[0:256], Bv = inputs @ edge_w1[256:512]
// Same register-blocked structure; bit-identical accumulation order.
// ---------------------------------------------------------------------------
__global__ __launch_bounds__(128) void k_tables(
    const float* __restrict__ x, const float* __restrict__ ew1,
    float* __restrict__ A, float* __restrict__ Bv)
{
  __shared__ float xs[RPB*260];   // 33.3 KB
  __shared__ float wsa[32*132];   // 16.9 KB
  __shared__ float wsb[32*132];   // 16.9 KB
  const int t=threadIdx.x, blk=blockIdx.x;
  const int b=blk/CHUNKS, chunk=blk%CHUNKS, row0=chunk*RPB;
  const int ri = t >> 4, ci = t & 15;

  { const float4* xg4=(const float4*)(x+((size_t)b*NN+row0)*FIN);
    #pragma unroll
    for (int p=0;p<16;p++){
      int idx4 = t + p*128;
      int r = idx4 >> 6, c4 = idx4 & 63;
      *(float4*)&xs[r*260 + c4*4] = xg4[idx4];
    } }

  float aA[4][8], aB[4][8];
  #pragma unroll
  for (int i=0;i<4;i++){
    #pragma unroll
    for (int j=0;j<8;j++){ aA[i][j]=0.f; aB[i][j]=0.f; } }
  __syncthreads();

  for (int kt=0; kt<8; ++kt){
    { const float4* wga = (const float4*)(ew1 + (size_t)kt*32*DD);
      const float4* wgb = (const float4*)(ew1 + (size_t)(FIN + kt*32)*DD);
      #pragma unroll
      for (int p=0;p<8;p++){
        int idx4 = t + p*128;
        int k = idx4 >> 5, c4 = idx4 & 31;
        *(float4*)&wsa[k*132 + c4*4] = wga[idx4];
        *(float4*)&wsb[k*132 + c4*4] = wgb[idx4];
      } }
    __syncthreads();
    #pragma unroll 4
    for (int kc=0; kc<32; kc+=4){
      float4 a4[4];
      #pragma unroll
      for (int i=0;i<4;i++) a4[i] = *(const float4*)&xs[(ri*4+i)*260 + kt*32 + kc];
      #pragma unroll
      for (int kk=0; kk<4; kk++){
        float4 alo = *(const float4*)&wsa[(kc+kk)*132 + ci*8];
        float4 ahi = *(const float4*)&wsa[(kc+kk)*132 + ci*8 + 4];
        float4 blo = *(const float4*)&wsb[(kc+kk)*132 + ci*8];
        float4 bhi = *(const float4*)&wsb[(kc+kk)*132 + ci*8 + 4];
        #pragma unroll
        for (int i=0;i<4;i++){
          float av = ((const float*)&a4[i])[kk];
          aA[i][0]=fmaf(av,alo.x,aA[i][0]); aA[i][1]=fmaf(av,alo.y,aA[i][1]);
          aA[i][2]=fmaf(av,alo.z,aA[i][2]); aA[i][3]=fmaf(av,alo.w,aA[i][3]);
          aA[i][4]=fmaf(av,ahi.x,aA[i][4]); aA[i][5]=fmaf(av,ahi.y,aA[i][5]);
          aA[i][6]=fmaf(av,ahi.z,aA[i][6]); aA[i][7]=fmaf(av,ahi.w,aA[i][7]);
          aB[i][0]=fmaf(av,blo.x,aB[i][0]); aB[i][1]=fmaf(av,blo.y,aB[i][1]);
          aB[i][2]=fmaf(av,blo.z,aB[i][2]); aB[i][3]=fmaf(av,blo.w,aB[i][3]);
          aB[i][4]=fmaf(av,bhi.x,aB[i][4]); aB[i][5]=fmaf(av,bhi.y,aB[i][5]);
          aB[i][6]=fmaf(av,bhi.z,aB[i][6]); aB[i][7]=fmaf(av,bhi.w,aB[i][7]);
        }
      }
    }
    __syncthreads();
  }

  #pragma unroll
  for (int i=0;i<4;i++){
    int r = ri*4+i;
    float* Ag = A  + ((size_t)b*NN+row0+r)*DD + ci*8;
    float* Bg = Bv + ((size_t)b*NN+row0+r)*DD + ci*8;
    #pragma unroll
    for (int j=0;j<8;j+=4){
      *(float4*)(Ag+j) = make_float4(aA[i][j],aA[i][j+1],aA[i][j+2],aA[i][j+3]);
      *(float4*)(Bg+j) = make_float4(aB[i][j],aB[i][j+1],aB[i][j+2],aB[i][j+3]);
    } }
}

// ---------------------------------------------------------------------------
// Kernel 3 (fused scan+scatter)
// ---------------------------------------------------------------------------
__global__ __launch_bounds__(256) void k_scan_scatter(
    const int* __restrict__ bin_idx, const int* __restrict__ localrank,
    const int* __restrict__ chunkhist, int* __restrict__ bs, float* __restrict__ out_bins)
{
  const int b=blockIdx.x, t=threadIdx.x;
  __shared__ int cbase_s[CHUNKS*NB];    // 16 KB
  __shared__ int tot[NB], start[NB];
  if (t<NB){
    int s=0;
    for (int c=0;c<CHUNKS;c++) s+=chunkhist[(b*CHUNKS+c)*NB+t];
    tot[t]=s;
  }
  __syncthreads();
  if (t==0){
    int run=0;
    for (int m=0;m<NB;m++){ start[m]=run; run+=tot[m]; }
  }
  __syncthreads();
  if (t<NB){
    int run=start[t];
    for (int c=0;c<CHUNKS;c++){
      cbase_s[c*NB+t]=run;
      run+=chunkhist[(b*CHUNKS+c)*NB+t];
    }
  }
  __syncthreads();
  for (int row=t; row<NN; row+=256){
    int gi=b*NN+row;
    int chunk=row>>5;
    int bi=bin_idx[gi];
    int pos=cbase_s[chunk*NB+bi]+localrank[gi];
    bs[b*NN+pos]=row;
    out_bins[b*NN+pos]=(float)row;
  }
}

// ---------------------------------------------------------------------------
// Kernel 4: per (batch, bin, 64-row tile) pairwise gaussian kernel + top-8.
// b128 LDS reads; CT k-index XOR-swizzled (<=2-way banks). Bit-identical FMA
// order (kk ascending) to the verified b32 version.
// ---------------------------------------------------------------------------
__global__ __launch_bounds__(256) void k_nn(
    const float* __restrict__ pe, const int* __restrict__ bs,
    float* __restrict__ out_idx, int* __restrict__ e_dst, float* __restrict__ e_val)
{
  __shared__ float RT[64*132];   // 33.8 KB (rows; later merge vals)
  __shared__ float CT[64*132];   // 33.8 KB (cols, k-swizzled; later merge idx)
  __shared__ float na_all[512];
  __shared__ int   bsl[BS];
  const int t=threadIdx.x;
  const int blk=blockIdx.x;                 // b*128 + bin*8 + rt
  const int rt=blk&7, bin=(blk>>3)&15, b=blk>>7;

  for (int i=t;i<BS;i+=256) bsl[i]=bs[b*NN + bin*BS + i];
  __syncthreads();

  for (int i=t;i<BS;i+=256){
    const float* pr = pe + ((size_t)b*NN + bsl[i])*DD;
    float s=0.f;
    for (int k=0;k<DD;k+=4){
      float4 v=*(const float4*)(pr+k);
      s=fmaf(v.x,v.x,s); s=fmaf(v.y,v.y,s); s=fmaf(v.z,v.z,s); s=fmaf(v.w,v.w,s);
    }
    na_all[i]=s;
  }

  const int r0=rt*64;
  const int nr=min(64, BS-r0);              // 64 or 52
  { const int lr=t>>5, c4=t&31;
    #pragma unroll
    for (int pass=0;pass<8;pass++){
      int r=pass*8+lr;
      float4 v=make_float4(0.f,0.f,0.f,0.f);
      if (r<nr) v=*(const float4*)(pe + ((size_t)b*NN + bsl[r0+r])*DD + c4*4);
      *(float4*)&RT[r*132 + c4*4] = v;
    } }

  float tv[4][8]; int tix[4][8];
  #pragma unroll
  for (int i=0;i<4;i++){
    #pragma unroll
    for (int s=0;s<8;s++){ tv[i][s]=-1e30f; tix[i][s]=0; } }

  const int tr_=t>>4, tc_=t&15;
  const int cswz = ((tc_>>1)&3)<<2;          // = ((col>>3)&3)<<2 for col=tc_*4+j

  for (int ct=0; ct<8; ++ct){
    __syncthreads();
    const int c0=ct*64;
    const int nc=min(64, BS-c0);
    { const int lr=t>>5, c4=t&31;
      #pragma unroll
      for (int pass=0;pass<8;pass++){
        int c=pass*8+lr;
        float4 v=make_float4(0.f,0.f,0.f,0.f);
        if (c<nc) v=*(const float4*)(pe + ((size_t)b*NN + bsl[c0+c])*DD + c4*4);
        int swz = ((c>>3)&3)<<2;
        *(float4*)&CT[c*132 + ((c4*4) ^ swz)] = v;
      } }
    __syncthreads();

    float accm[4][4];
    #pragma unroll
    for (int i=0;i<4;i++){
      #pragma unroll
      for (int j=0;j<4;j++) accm[i][j]=0.f; }

    #pragma unroll 8
    for (int k0=0;k0<DD;k0+=4){
      float4 a4[4], b4[4];
      #pragma unroll
      for (int i=0;i<4;i++) a4[i]=*(const float4*)&RT[(tr_*4+i)*132 + k0];
      #pragma unroll
      for (int j=0;j<4;j++) b4[j]=*(const float4*)&CT[(tc_*4+j)*132 + (k0 ^ cswz)];
      #pragma unroll
      for (int kk=0;kk<4;kk++){
        #pragma unroll
        for (int i=0;i<4;i++){
          float av=((const float*)&a4[i])[kk];
          #pragma unroll
          for (int j=0;j<4;j++){
            float bvv=((const float*)&b4[j])[kk];
            accm[i][j]=fmaf(av,bvv,accm[i][j]);
          }
        }
      }
    }

    float nrow[4], ncol[4];
    #pragma unroll
    for (int i=0;i<4;i++) nrow[i]=na_all[r0+tr_*4+i];
    #pragma unroll
    for (int j=0;j<4;j++) ncol[j]=na_all[c0+tc_*4+j];

    #pragma unroll
    for (int i=0;i<4;i++){
      #pragma unroll
      for (int j=0;j<4;j++){
        float t1=nrow[i]-2.f*accm[i][j];
        float d2v=t1+ncol[j];
        float dm=expf(-0.1f*sqrtf(fmaxf(d2v,1e-6f)));
        int c=c0+tc_*4+j;
        if (c<BS && dm>tv[i][7]){
          tv[i][7]=dm; tix[i][7]=c;
          #pragma unroll
          for (int q=7;q>0;q--){
            if (tv[i][q]>tv[i][q-1]){
              float tf=tv[i][q];tv[i][q]=tv[i][q-1];tv[i][q-1]=tf;
              int   td=tix[i][q];tix[i][q]=tix[i][q-1];tix[i][q-1]=td;
            }
          }
        }
      }
    }
  }

  __syncthreads();
  #pragma unroll
  for (int i=0;i<4;i++){
    const int row=tr_*4+i;
    #pragma unroll
    for (int s=0;s<8;s++){
      RT[row*132 + tc_*8 + s]=tv[i][s];
      CT[row*132 + tc_*8 + s]=__int_as_float(tix[i][s]);
    }
  }
  __syncthreads();

  if (t<nr){
    float mv[8]; int mi[8];
    #pragma unroll
    for (int s=0;s<8;s++){ mv[s]=-1e30f; mi[s]=0; }
    for (int p=0;p<128;p++){
      float v=RT[t*132+p]; int c=__float_as_int(CT[t*132+p]);
      if (v>mv[7] || (v==mv[7] && c<mi[7])){
        mv[7]=v; mi[7]=c;
        #pragma unroll
        for (int q=7;q>0;q--){
          bool sw=(mv[q]>mv[q-1]) || (mv[q]==mv[q-1] && mi[q]<mi[q-1]);
          if (sw){
            float tf=mv[q];mv[q]=mv[q-1];mv[q-1]=tf;
            int   td=mi[q];mi[q]=mi[q-1];mi[q-1]=td;
          }
        }
      }
    }
    const int src=bsl[r0+t];
    int dsts[KK]; float vv[KK];
    #pragma unroll
    for (int k2=0;k2<KK;k2++){ dsts[k2]=bsl[mi[k2]]; vv[k2]=mv[k2]; }
    #define CSWAP(a_,b_) { if (dsts[a_]>dsts[b_]){ int td=dsts[a_];dsts[a_]=dsts[b_];dsts[b_]=td; float tf=vv[a_];vv[a_]=vv[b_];vv[b_]=tf; } }
    CSWAP(0,1) CSWAP(2,3) CSWAP(4,5) CSWAP(6,7)
    CSWAP(0,2) CSWAP(1,3) CSWAP(4,6) CSWAP(5,7)
    CSWAP(1,2) CSWAP(5,6)
    CSWAP(0,4) CSWAP(1,5) CSWAP(2,6) CSWAP(3,7)
    CSWAP(2,4) CSWAP(3,5)
    CSWAP(1,2) CSWAP(3,4) CSWAP(5,6)
    #undef CSWAP
    size_t e0=((size_t)b*NN + src)*KK;
    #pragma unroll
    for (int k2=0;k2<KK;k2++){
      out_idx[3*(e0+k2)+0]=(float)b;
      out_idx[3*(e0+k2)+1]=(float)src;
      out_idx[3*(e0+k2)+2]=(float)dsts[k2];
      e_dst[e0+k2]=dsts[k2];
      e_val[e0+k2]=vv[k2];
    }
  }
}

// ---------------------------------------------------------------------------
// Kernel 5: edge MLP. One wave per (b,src) group of 8 edges.
// ---------------------------------------------------------------------------
__global__ __launch_bounds__(256) void k_edge(
    const float* __restrict__ A, const float* __restrict__ Bv,
    const float* __restrict__ ew1, const float* __restrict__ eb1,
    const float* __restrict__ ew2, const float* __restrict__ eb2,
    const int* __restrict__ e_dst, const float* __restrict__ e_val,
    float* __restrict__ out_vals)
{
  const int wid = (int)((blockIdx.x*256u+threadIdx.x)>>6);
  const int lane = threadIdx.x&63;
  if (wid >= BB*NN) return;
  const int b = wid / NN;
  const float2 a2  = *(const float2*)(A   + (size_t)wid*DD + lane*2);
  const float2 wc  = *(const float2*)(ew1 + (size_t)512*DD + lane*2);
  const float2 bb1 = *(const float2*)(eb1 + lane*2);
  const float2 w2v = *(const float2*)(ew2 + lane*2);
  const float  b2s = eb2[0];
  const size_t e0 = (size_t)wid*KK;
  #pragma unroll
  for (int k=0;k<KK;k++){
    int dst = e_dst[e0+k];
    float val = e_val[e0+k];
    const float2 bv = *(const float2*)(Bv + ((size_t)b*NN+dst)*DD + lane*2);
    float h0 = a2.x + bv.x + val*wc.x + bb1.x;  h0 = h0>0.f ? h0 : expm1f(h0);
    float h1 = a2.y + bv.y + val*wc.y + bb1.y;  h1 = h1>0.f ? h1 : expm1f(h1);
    float s = h0*w2v.x + h1*w2v.y;
    #pragma unroll
    for (int off=32; off; off>>=1) s += __shfl_xor(s, off);
    if (lane==k) out_vals[e0+k] = 1.f/(1.f+expf(-(s+b2s)));
  }
}

// ---------------------------------------------------------------------------
extern "C" void kernel_launch(void* const* d_in, const int* in_sizes, int n_in,
                              void* d_out, int out_size, void* d_ws, size_t ws_size,
                              hipStream_t stream)
{
  const float* x    = (const float*)d_in[0];
  const float* ew1v = (const float*)d_in[1];
  const float* eb1v = (const float*)d_in[2];
  const float* ew2v = (const float*)d_in[3];
  const float* eb2v = (const float*)d_in[4];
  const float* gw1  = (const float*)d_in[5];
  const float* gb1  = (const float*)d_in[6];
  const float* gw2  = (const float*)d_in[7];
  const float* gb2  = (const float*)d_in[8];
  const float* rot  = (const float*)d_in[9];

  char* w = (char*)d_ws;
  float* pe   = (float*)w;  w += (size_t)BB*NN*DD*4;
  float* Atab = (float*)w;  w += (size_t)BB*NN*DD*4;
  float* Btab = (float*)w;  w += (size_t)BB*NN*DD*4;
  int*   bin_idx   = (int*)w; w += (size_t)BB*NN*4;
  int*   localrank = (int*)w; w += (size_t)BB*NN*4;
  int*   chunkhist = (int*)w; w += (size_t)BB*CHUNKS*NB*4;
  int*   bs        = (int*)w; w += (size_t)BB*NN*4;
  int*   e_dst     = (int*)w; w += (size_t)ETOT*4;
  float* e_val     = (float*)w; w += (size_t)ETOT*4;

  float* out_idx  = (float*)d_out;
  float* out_vals = out_idx + (size_t)ETOT*3;
  float* out_bins = out_vals + ETOT;

  k_encode<<<dim3(BB*CHUNKS), dim3(128), 0, stream>>>(
      x, ew1v, eb1v, ew2v, eb2v, rot, pe, bin_idx, localrank, chunkhist);
  k_tables<<<dim3(BB*CHUNKS), dim3(128), 0, stream>>>(x, gw1, Atab, Btab);
  k_scan_scatter<<<dim3(BB), dim3(256), 0, stream>>>(
      bin_idx, localrank, chunkhist, bs, out_bins);
  k_nn<<<dim3(BB*NB*8), dim3(256), 0, stream>>>(pe, bs, out_idx, e_dst, e_val);
  k_edge<<<dim3(BB*NN/4), dim3(256), 0, stream>>>(
      Atab, Btab, gw1, gb1, gw2, gb2, e_dst, e_val, out_vals);
}

// Round 4
// 514.371 us; speedup vs baseline: 1.3419x; 1.0298x over previous
//
#include <hip/hip_runtime.h>
#include <math.h>

#define BB 4
#define NN 8000
#define FIN 256
#define DD 128
#define NB 16
#define BS 500
#define KK 8
#define RPB 32
#define CHUNKS (NN/RPB)   /* 250 */
#define ETOT (BB*NN*KK)   /* 256000 */

// ---------------------------------------------------------------------------
// Kernel 1 (fused): encode FFN (256->128 elu->128) + LSH binning + edge tables
// A = x@ew1[0:256], Bv = x@ew1[256:512].  256 threads, 32 rows/block.
// No activation LDS: x read from global (L1 broadcast). Weight k-tiles double-
// buffered in LDS with async prefetch. FMA order bit-identical to verified ver.
// ---------------------------------------------------------------------------
__global__ __launch_bounds__(256) void k_fused(
    const float* __restrict__ x, const float* __restrict__ w1, const float* __restrict__ b1,
    const float* __restrict__ w2, const float* __restrict__ b2, const float* __restrict__ rot,
    const float* __restrict__ ew1,
    float* __restrict__ pe, float* __restrict__ A, float* __restrict__ Bv,
    int* __restrict__ bin_idx, int* __restrict__ localrank, int* __restrict__ chunkhist)
{
  __shared__ float wsa[32*132];   // 16.9 KB
  __shared__ float wsb[32*132];   // 16.9 KB
  __shared__ float ps[RPB*132];   // 16.9 KB (h, then pe)
  __shared__ float ms[RPB*9];
  __shared__ int   bl[RPB];
  const int t = threadIdx.x;
  const int b = blockIdx.x / CHUNKS;
  const int chunk = blockIdx.x % CHUNKS;
  const int row0 = chunk * RPB;
  const int ri = t >> 4;            // 0..15 -> rows ri*2, ri*2+1
  const int ci = t & 15;            // 0..15 -> cols ci*8..+7
  const int r0t = ri*2, r1t = ri*2+1;
  const float* xrow0 = x + ((size_t)b*NN + row0 + r0t)*FIN;
  const float* xrow1 = x + ((size_t)b*NN + row0 + r1t)*FIN;
  // staging indices: thread stages 4 float4; k_p = p*8 + (t>>5), c4 = t&31
  const int sk = t >> 5, sc4 = t & 31;

  // ================= layer 1: K=256, 8 tiles =================
  float acc0[8], acc1[8];
  #pragma unroll
  for (int j=0;j<8;j++){ float bb = b1[ci*8+j]; acc0[j]=bb; acc1[j]=bb; }

  float4 rw0,rw1,rw2,rw3;
  { const float4* wg = (const float4*)w1;
    rw0=wg[t]; rw1=wg[t+256]; rw2=wg[t+512]; rw3=wg[t+768]; }
  int cur = 0;
  for (int kt=0; kt<8; ++kt){
    float* wsc = cur ? wsb : wsa;
    *(float4*)&wsc[(sk   )*132 + sc4*4] = rw0;
    *(float4*)&wsc[(sk+ 8)*132 + sc4*4] = rw1;
    *(float4*)&wsc[(sk+16)*132 + sc4*4] = rw2;
    *(float4*)&wsc[(sk+24)*132 + sc4*4] = rw3;
    if (kt<7){ const float4* wg = (const float4*)(w1 + (size_t)(kt+1)*32*DD);
      rw0=wg[t]; rw1=wg[t+256]; rw2=wg[t+512]; rw3=wg[t+768]; }
    __syncthreads();
    const float* xp0 = xrow0 + kt*32;
    const float* xp1 = xrow1 + kt*32;
    #pragma unroll
    for (int kc=0;kc<32;kc+=4){
      float4 a0 = *(const float4*)(xp0+kc);
      float4 a1 = *(const float4*)(xp1+kc);
      #pragma unroll
      for (int kk=0;kk<4;kk++){
        float4 wlo = *(const float4*)&wsc[(kc+kk)*132 + ci*8];
        float4 whi = *(const float4*)&wsc[(kc+kk)*132 + ci*8 + 4];
        float a0v = ((const float*)&a0)[kk], a1v = ((const float*)&a1)[kk];
        acc0[0]=fmaf(a0v,wlo.x,acc0[0]); acc0[1]=fmaf(a0v,wlo.y,acc0[1]);
        acc0[2]=fmaf(a0v,wlo.z,acc0[2]); acc0[3]=fmaf(a0v,wlo.w,acc0[3]);
        acc0[4]=fmaf(a0v,whi.x,acc0[4]); acc0[5]=fmaf(a0v,whi.y,acc0[5]);
        acc0[6]=fmaf(a0v,whi.z,acc0[6]); acc0[7]=fmaf(a0v,whi.w,acc0[7]);
        acc1[0]=fmaf(a1v,wlo.x,acc1[0]); acc1[1]=fmaf(a1v,wlo.y,acc1[1]);
        acc1[2]=fmaf(a1v,wlo.z,acc1[2]); acc1[3]=fmaf(a1v,wlo.w,acc1[3]);
        acc1[4]=fmaf(a1v,whi.x,acc1[4]); acc1[5]=fmaf(a1v,whi.y,acc1[5]);
        acc1[6]=fmaf(a1v,whi.z,acc1[6]); acc1[7]=fmaf(a1v,whi.w,acc1[7]);
      }
    }
    cur ^= 1;
  }
  // elu -> ps (h)
  #pragma unroll
  for (int j=0;j<8;j++){
    float v0=acc0[j]; ps[r0t*132 + ci*8 + j] = v0>0.f ? v0 : expm1f(v0);
    float v1=acc1[j]; ps[r1t*132 + ci*8 + j] = v1>0.f ? v1 : expm1f(v1);
  }

  // ================= layer 2: K=128, 4 tiles =================
  float acc20[8], acc21[8];
  #pragma unroll
  for (int j=0;j<8;j++){ float bb = b2[ci*8+j]; acc20[j]=bb; acc21[j]=bb; }
  { const float4* wg = (const float4*)w2;
    rw0=wg[t]; rw1=wg[t+256]; rw2=wg[t+512]; rw3=wg[t+768]; }
  for (int kt=0; kt<4; ++kt){
    float* wsc = cur ? wsb : wsa;
    *(float4*)&wsc[(sk   )*132 + sc4*4] = rw0;
    *(float4*)&wsc[(sk+ 8)*132 + sc4*4] = rw1;
    *(float4*)&wsc[(sk+16)*132 + sc4*4] = rw2;
    *(float4*)&wsc[(sk+24)*132 + sc4*4] = rw3;
    if (kt<3){ const float4* wg = (const float4*)(w2 + (size_t)(kt+1)*32*DD);
      rw0=wg[t]; rw1=wg[t+256]; rw2=wg[t+512]; rw3=wg[t+768]; }
    __syncthreads();   // ws ready; also makes ps (h) visible at kt==0
    #pragma unroll
    for (int kc=0;kc<32;kc+=4){
      float4 a0 = *(const float4*)&ps[r0t*132 + kt*32 + kc];
      float4 a1 = *(const float4*)&ps[r1t*132 + kt*32 + kc];
      #pragma unroll
      for (int kk=0;kk<4;kk++){
        float4 wlo = *(const float4*)&wsc[(kc+kk)*132 + ci*8];
        float4 whi = *(const float4*)&wsc[(kc+kk)*132 + ci*8 + 4];
        float a0v = ((const float*)&a0)[kk], a1v = ((const float*)&a1)[kk];
        acc20[0]=fmaf(a0v,wlo.x,acc20[0]); acc20[1]=fmaf(a0v,wlo.y,acc20[1]);
        acc20[2]=fmaf(a0v,wlo.z,acc20[2]); acc20[3]=fmaf(a0v,wlo.w,acc20[3]);
        acc20[4]=fmaf(a0v,whi.x,acc20[4]); acc20[5]=fmaf(a0v,whi.y,acc20[5]);
        acc20[6]=fmaf(a0v,whi.z,acc20[6]); acc20[7]=fmaf(a0v,whi.w,acc20[7]);
        acc21[0]=fmaf(a1v,wlo.x,acc21[0]); acc21[1]=fmaf(a1v,wlo.y,acc21[1]);
        acc21[2]=fmaf(a1v,wlo.z,acc21[2]); acc21[3]=fmaf(a1v,wlo.w,acc21[3]);
        acc21[4]=fmaf(a1v,whi.x,acc21[4]); acc21[5]=fmaf(a1v,whi.y,acc21[5]);
        acc21[6]=fmaf(a1v,whi.z,acc21[6]); acc21[7]=fmaf(a1v,whi.w,acc21[7]);
      }
    }
    cur ^= 1;
  }
  __syncthreads();   // all ps(h) readers done before overwrite with pe

  // write pe to global + ps
  { float* pg0 = pe + ((size_t)b*NN + row0 + r0t)*DD + ci*8;
    float* pg1 = pe + ((size_t)b*NN + row0 + r1t)*DD + ci*8;
    #pragma unroll
    for (int j=0;j<8;j+=4){
      float4 v0 = make_float4(acc20[j],acc20[j+1],acc20[j+2],acc20[j+3]);
      float4 v1 = make_float4(acc21[j],acc21[j+1],acc21[j+2],acc21[j+3]);
      *(float4*)(pg0+j)=v0; *(float4*)&ps[r0t*132 + ci*8 + j]=v0;
      *(float4*)(pg1+j)=v1; *(float4*)&ps[r1t*132 + ci*8 + j]=v1;
    } }

  // ================= edge tables: K=256, 8 tiles, dual weights =============
  float aA0[8], aA1[8], aB0[8], aB1[8];
  #pragma unroll
  for (int j=0;j<8;j++){ aA0[j]=0.f; aA1[j]=0.f; aB0[j]=0.f; aB1[j]=0.f; }
  float4 ra0,ra1,ra2,ra3, rb0,rb1,rb2,rb3;
  { const float4* wga = (const float4*)ew1;
    const float4* wgb = (const float4*)(ew1 + (size_t)FIN*DD);
    ra0=wga[t]; ra1=wga[t+256]; ra2=wga[t+512]; ra3=wga[t+768];
    rb0=wgb[t]; rb1=wgb[t+256]; rb2=wgb[t+512]; rb3=wgb[t+768]; }
  for (int kt=0; kt<8; ++kt){
    __syncthreads();   // previous GEMM readers done (first: pe/ps writes visible)
    *(float4*)&wsa[(sk   )*132 + sc4*4] = ra0;
    *(float4*)&wsa[(sk+ 8)*132 + sc4*4] = ra1;
    *(float4*)&wsa[(sk+16)*132 + sc4*4] = ra2;
    *(float4*)&wsa[(sk+24)*132 + sc4*4] = ra3;
    *(float4*)&wsb[(sk   )*132 + sc4*4] = rb0;
    *(float4*)&wsb[(sk+ 8)*132 + sc4*4] = rb1;
    *(float4*)&wsb[(sk+16)*132 + sc4*4] = rb2;
    *(float4*)&wsb[(sk+24)*132 + sc4*4] = rb3;
    if (kt<7){
      const float4* wga = (const float4*)(ew1 + (size_t)(kt+1)*32*DD);
      const float4* wgb = (const float4*)(ew1 + (size_t)(FIN + (kt+1)*32)*DD);
      ra0=wga[t]; ra1=wga[t+256]; ra2=wga[t+512]; ra3=wga[t+768];
      rb0=wgb[t]; rb1=wgb[t+256]; rb2=wgb[t+512]; rb3=wgb[t+768]; }
    __syncthreads();   // ws ready
    const float* xp0 = xrow0 + kt*32;
    const float* xp1 = xrow1 + kt*32;
    #pragma unroll
    for (int kc=0;kc<32;kc+=4){
      float4 a0 = *(const float4*)(xp0+kc);
      float4 a1 = *(const float4*)(xp1+kc);
      #pragma unroll
      for (int kk=0;kk<4;kk++){
        float4 alo = *(const float4*)&wsa[(kc+kk)*132 + ci*8];
        float4 ahi = *(const float4*)&wsa[(kc+kk)*132 + ci*8 + 4];
        float4 blo = *(const float4*)&wsb[(kc+kk)*132 + ci*8];
        float4 bhi = *(const float4*)&wsb[(kc+kk)*132 + ci*8 + 4];
        float a0v = ((const float*)&a0)[kk], a1v = ((const float*)&a1)[kk];
        aA0[0]=fmaf(a0v,alo.x,aA0[0]); aA0[1]=fmaf(a0v,alo.y,aA0[1]);
        aA0[2]=fmaf(a0v,alo.z,aA0[2]); aA0[3]=fmaf(a0v,alo.w,aA0[3]);
        aA0[4]=fmaf(a0v,ahi.x,aA0[4]); aA0[5]=fmaf(a0v,ahi.y,aA0[5]);
        aA0[6]=fmaf(a0v,ahi.z,aA0[6]); aA0[7]=fmaf(a0v,ahi.w,aA0[7]);
        aA1[0]=fmaf(a1v,alo.x,aA1[0]); aA1[1]=fmaf(a1v,alo.y,aA1[1]);
        aA1[2]=fmaf(a1v,alo.z,aA1[2]); aA1[3]=fmaf(a1v,alo.w,aA1[3]);
        aA1[4]=fmaf(a1v,ahi.x,aA1[4]); aA1[5]=fmaf(a1v,ahi.y,aA1[5]);
        aA1[6]=fmaf(a1v,ahi.z,aA1[6]); aA1[7]=fmaf(a1v,ahi.w,aA1[7]);
        aB0[0]=fmaf(a0v,blo.x,aB0[0]); aB0[1]=fmaf(a0v,blo.y,aB0[1]);
        aB0[2]=fmaf(a0v,blo.z,aB0[2]); aB0[3]=fmaf(a0v,blo.w,aB0[3]);
        aB0[4]=fmaf(a0v,bhi.x,aB0[4]); aB0[5]=fmaf(a0v,bhi.y,aB0[5]);
        aB0[6]=fmaf(a0v,bhi.z,aB0[6]); aB0[7]=fmaf(a0v,bhi.w,aB0[7]);
        aB1[0]=fmaf(a1v,blo.x,aB1[0]); aB1[1]=fmaf(a1v,blo.y,aB1[1]);
        aB1[2]=fmaf(a1v,blo.z,aB1[2]); aB1[3]=fmaf(a1v,blo.w,aB1[3]);
        aB1[4]=fmaf(a1v,bhi.x,aB1[4]); aB1[5]=fmaf(a1v,bhi.y,aB1[5]);
        aB1[6]=fmaf(a1v,bhi.z,aB1[6]); aB1[7]=fmaf(a1v,bhi.w,aB1[7]);
      }
    }
  }
  { float* Ag0 = A  + ((size_t)b*NN+row0+r0t)*DD + ci*8;
    float* Ag1 = A  + ((size_t)b*NN+row0+r1t)*DD + ci*8;
    float* Bg0 = Bv + ((size_t)b*NN+row0+r0t)*DD + ci*8;
    float* Bg1 = Bv + ((size_t)b*NN+row0+r1t)*DD + ci*8;
    #pragma unroll
    for (int j=0;j<8;j+=4){
      *(float4*)(Ag0+j)=make_float4(aA0[j],aA0[j+1],aA0[j+2],aA0[j+3]);
      *(float4*)(Ag1+j)=make_float4(aA1[j],aA1[j+1],aA1[j+2],aA1[j+3]);
      *(float4*)(Bg0+j)=make_float4(aB0[j],aB0[j+1],aB0[j+2],aB0[j+3]);
      *(float4*)(Bg1+j)=make_float4(aB1[j],aB1[j+1],aB1[j+2],aB1[j+3]);
    } }

  // ================= LSH binning (identical math to verified version) ======
  if (t<128){
    const int r = t>>2, m0 = t&3;
    float s0=0.f, s1=0.f;
    for (int k=0;k<DD;k++){
      float p = ps[r*132+k];
      s0 = fmaf(p, rot[k*100+m0],   s0);
      s1 = fmaf(p, rot[k*100+m0+4], s1);
    }
    ms[r*9+m0]=s0; ms[r*9+m0+4]=s1;
  }
  __syncthreads();
  if (t<RPB){
    float best = ms[t*9+0]; int bi=0;
    #pragma unroll
    for (int m=1;m<16;m++){
      float v = (m<8)? ms[t*9+m] : -ms[t*9+(m-8)];
      if (v>best){best=v;bi=m;}
    }
    bl[t]=bi;
    bin_idx[b*NN+row0+t]=bi;
  }
  __syncthreads();
  if (t<RPB){
    int myb=bl[t]; int rk=0;
    for (int r2=0;r2<t;r2++) rk += (bl[r2]==myb) ? 1 : 0;
    localrank[b*NN+row0+t]=rk;
  }
  if (t<NB){
    int cnt=0;
    #pragma unroll
    for (int r2=0;r2<RPB;r2++) cnt += (bl[r2]==t) ? 1 : 0;
    chunkhist[(b*CHUNKS+chunk)*NB + t] = cnt;
  }
}

// ---------------------------------------------------------------------------
// Kernel 2: fused parallel scan + stable scatter
// ---------------------------------------------------------------------------
__global__ __launch_bounds__(256) void k_scan_scatter(
    const int* __restrict__ bin_idx, const int* __restrict__ localrank,
    const int* __restrict__ chunkhist, int* __restrict__ bs, float* __restrict__ out_bins)
{
  const int b=blockIdx.x, t=threadIdx.x;
  __shared__ int cbase_s[CHUNKS*NB];    // 16 KB
  __shared__ int segsum[16*NB];
  __shared__ int start[NB];
  const int m = t&15, s = t>>4;         // 16 segs x 16 bins
  const int c0 = s*16, c1 = min(c0+16, CHUNKS);
  { int run=0;
    for (int c=c0;c<c1;c++) run += chunkhist[(b*CHUNKS+c)*NB+m];
    segsum[s*NB+m]=run; }
  __syncthreads();
  if (t<NB){
    int acc=0;
    for (int s2=0;s2<16;s2++){ int v=segsum[s2*NB+t]; segsum[s2*NB+t]=acc; acc+=v; }
    start[t]=acc;                       // per-bin total (temp)
  }
  __syncthreads();
  if (t==0){
    int run=0;
    for (int mm=0;mm<NB;mm++){ int tt=start[mm]; start[mm]=run; run+=tt; }
  }
  __syncthreads();
  { int acc = start[m] + segsum[s*NB+m];
    for (int c=c0;c<c1;c++){
      cbase_s[c*NB+m]=acc;
      acc += chunkhist[(b*CHUNKS+c)*NB+m];
    } }
  __syncthreads();
  for (int row=t; row<NN; row+=256){
    int gi=b*NN+row;
    int chunk=row>>5;                   // RPB==32
    int bi=bin_idx[gi];
    int pos=cbase_s[chunk*NB+bi]+localrank[gi];
    bs[b*NN+pos]=row;
    out_bins[b*NN+pos]=(float)row;
  }
}

// ---------------------------------------------------------------------------
// Kernel 3: per (batch, bin, 64-row tile) pairwise gaussian kernel + top-8.
// T14 async-STAGE for CT (prefetch regs before GEMM, ds_write after barrier);
// transposed merge scratch (stride 65, conflict-free). Math bit-identical.
// ---------------------------------------------------------------------------
__global__ __launch_bounds__(256) void k_nn(
    const float* __restrict__ pe, const int* __restrict__ bs,
    float* __restrict__ out_idx, int* __restrict__ e_dst, float* __restrict__ e_val)
{
  __shared__ float RT[64*132];   // 33.8 KB (row tile; later merge vals [128][65])
  __shared__ float CT[64*132];   // 33.8 KB (col tile swizzled; later merge idx)
  __shared__ float na_all[512];
  __shared__ int   bsl[BS];
  const int t=threadIdx.x;
  const int blk=blockIdx.x;                 // b*128 + bin*8 + rt
  const int rt=blk&7, bin=(blk>>3)&15, b=blk>>7;

  for (int i=t;i<BS;i+=256) bsl[i]=bs[b*NN + bin*BS + i];
  __syncthreads();

  // squared norms (same sequential accumulation as verified version)
  for (int i=t;i<BS;i+=256){
    const float* pr = pe + ((size_t)b*NN + bsl[i])*DD;
    float s=0.f;
    for (int k=0;k<DD;k+=4){
      float4 v=*(const float4*)(pr+k);
      s=fmaf(v.x,v.x,s); s=fmaf(v.y,v.y,s); s=fmaf(v.z,v.z,s); s=fmaf(v.w,v.w,s);
    }
    na_all[i]=s;
  }

  const int r0=rt*64;
  const int nr=min(64, BS-r0);              // 64 or 52
  const int lr=t>>5, c4=t&31;
  #pragma unroll
  for (int pass=0;pass<8;pass++){
    int r=pass*8+lr;
    float4 v=make_float4(0.f,0.f,0.f,0.f);
    if (r<nr) v=*(const float4*)(pe + ((size_t)b*NN + bsl[r0+r])*DD + c4*4);
    *(float4*)&RT[r*132 + c4*4] = v;
  }
  // preload CT tile 0 into regs
  float4 creg[8];
  #pragma unroll
  for (int pass=0;pass<8;pass++){
    int c=pass*8+lr;
    creg[pass]=*(const float4*)(pe + ((size_t)b*NN + bsl[c])*DD + c4*4);  // nc=64 for ct=0
  }
  __syncthreads();      // RT + na visible
  #pragma unroll
  for (int pass=0;pass<8;pass++){
    int c=pass*8+lr; int swz=((c>>3)&3)<<2;
    *(float4*)&CT[c*132 + ((c4*4) ^ swz)] = creg[pass];
  }
  __syncthreads();      // CT0 ready

  float tv[4][8]; int tix[4][8];
  #pragma unroll
  for (int i=0;i<4;i++){
    #pragma unroll
    for (int s=0;s<8;s++){ tv[i][s]=-1e30f; tix[i][s]=0; } }

  const int tr_=t>>4, tc_=t&15;
  const int cswz = ((tc_>>1)&3)<<2;

  for (int ct=0; ct<8; ++ct){
    const int c0=ct*64;
    // prefetch next column tile into regs (latency hides under GEMM)
    if (ct<7){
      const int c0n=c0+64;
      const int ncn=min(64, BS-c0n);
      #pragma unroll
      for (int pass=0;pass<8;pass++){
        int c=pass*8+lr;
        creg[pass]=make_float4(0.f,0.f,0.f,0.f);
        if (c<ncn) creg[pass]=*(const float4*)(pe + ((size_t)b*NN + bsl[c0n+c])*DD + c4*4);
      }
    }

    float accm[4][4];
    #pragma unroll
    for (int i=0;i<4;i++){
      #pragma unroll
      for (int j=0;j<4;j++) accm[i][j]=0.f; }
    #pragma unroll 8
    for (int k0=0;k0<DD;k0+=4){
      float4 a4[4], b4[4];
      #pragma unroll
      for (int i=0;i<4;i++) a4[i]=*(const float4*)&RT[(tr_*4+i)*132 + k0];
      #pragma unroll
      for (int j=0;j<4;j++) b4[j]=*(const float4*)&CT[(tc_*4+j)*132 + (k0 ^ cswz)];
      #pragma unroll
      for (int kk=0;kk<4;kk++){
        #pragma unroll
        for (int i=0;i<4;i++){
          float av=((const float*)&a4[i])[kk];
          #pragma unroll
          for (int j=0;j<4;j++){
            float bvv=((const float*)&b4[j])[kk];
            accm[i][j]=fmaf(av,bvv,accm[i][j]);
          }
        }
      }
    }

    float nrow[4], ncol[4];
    #pragma unroll
    for (int i=0;i<4;i++) nrow[i]=na_all[r0+tr_*4+i];
    #pragma unroll
    for (int j=0;j<4;j++) ncol[j]=na_all[c0+tc_*4+j];

    #pragma unroll
    for (int i=0;i<4;i++){
      #pragma unroll
      for (int j=0;j<4;j++){
        float t1=nrow[i]-2.f*accm[i][j];
        float d2v=t1+ncol[j];
        float dm=expf(-0.1f*sqrtf(fmaxf(d2v,1e-6f)));
        int c=c0+tc_*4+j;
        if (c<BS && dm>tv[i][7]){          // strict > : lax.top_k tie semantics
          tv[i][7]=dm; tix[i][7]=c;
          #pragma unroll
          for (int q=7;q>0;q--){
            if (tv[i][q]>tv[i][q-1]){
              float tf=tv[i][q];tv[i][q]=tv[i][q-1];tv[i][q-1]=tf;
              int   td=tix[i][q];tix[i][q]=tix[i][q-1];tix[i][q-1]=td;
            }
          }
        }
      }
    }
    __syncthreads();               // all CT readers done
    if (ct<7){
      #pragma unroll
      for (int pass=0;pass<8;pass++){
        int c=pass*8+lr; int swz=((c>>3)&3)<<2;
        *(float4*)&CT[c*132 + ((c4*4) ^ swz)] = creg[pass];
      }
      __syncthreads();             // next CT ready
    }
  }

  // dump partial lists TRANSPOSED: vals RT[p*65+row], idx CT[p*65+row]
  #pragma unroll
  for (int i=0;i<4;i++){
    const int row=tr_*4+i;
    #pragma unroll
    for (int s=0;s<8;s++){
      const int p=tc_*8+s;
      RT[p*65 + row]=tv[i][s];
      CT[p*65 + row]=__int_as_float(tix[i][s]);
    }
  }
  __syncthreads();

  if (t<nr){
    float mv[8]; int mi[8];
    #pragma unroll
    for (int s=0;s<8;s++){ mv[s]=-1e30f; mi[s]=0; }
    #pragma unroll 4
    for (int p=0;p<128;p++){
      float v=RT[p*65+t]; int c=__float_as_int(CT[p*65+t]);
      if (v>mv[7] || (v==mv[7] && c<mi[7])){
        mv[7]=v; mi[7]=c;
        #pragma unroll
        for (int q=7;q>0;q--){
          bool sw=(mv[q]>mv[q-1]) || (mv[q]==mv[q-1] && mi[q]<mi[q-1]);
          if (sw){
            float tf=mv[q];mv[q]=mv[q-1];mv[q-1]=tf;
            int   td=mi[q];mi[q]=mi[q-1];mi[q-1]=td;
          }
        }
      }
    }
    const int src=bsl[r0+t];
    int dsts[KK]; float vv[KK];
    #pragma unroll
    for (int k2=0;k2<KK;k2++){ dsts[k2]=bsl[mi[k2]]; vv[k2]=mv[k2]; }
    #define CSWAP(a_,b_) { if (dsts[a_]>dsts[b_]){ int td=dsts[a_];dsts[a_]=dsts[b_];dsts[b_]=td; float tf=vv[a_];vv[a_]=vv[b_];vv[b_]=tf; } }
    CSWAP(0,1) CSWAP(2,3) CSWAP(4,5) CSWAP(6,7)
    CSWAP(0,2) CSWAP(1,3) CSWAP(4,6) CSWAP(5,7)
    CSWAP(1,2) CSWAP(5,6)
    CSWAP(0,4) CSWAP(1,5) CSWAP(2,6) CSWAP(3,7)
    CSWAP(2,4) CSWAP(3,5)
    CSWAP(1,2) CSWAP(3,4) CSWAP(5,6)
    #undef CSWAP
    size_t e0=((size_t)b*NN + src)*KK;
    #pragma unroll
    for (int k2=0;k2<KK;k2++){
      out_idx[3*(e0+k2)+0]=(float)b;
      out_idx[3*(e0+k2)+1]=(float)src;
      out_idx[3*(e0+k2)+2]=(float)dsts[k2];
      e_dst[e0+k2]=dsts[k2];
      e_val[e0+k2]=vv[k2];
    }
  }
}

// ---------------------------------------------------------------------------
// Kernel 4: edge MLP. One wave per (b,src) group of 8 edges.
// ---------------------------------------------------------------------------
__global__ __launch_bounds__(256) void k_edge(
    const float* __restrict__ A, const float* __restrict__ Bv,
    const float* __restrict__ ew1, const float* __restrict__ eb1,
    const float* __restrict__ ew2, const float* __restrict__ eb2,
    const int* __restrict__ e_dst, const float* __restrict__ e_val,
    float* __restrict__ out_vals)
{
  const int wid = (int)((blockIdx.x*256u+threadIdx.x)>>6);
  const int lane = threadIdx.x&63;
  if (wid >= BB*NN) return;
  const int b = wid / NN;
  const float2 a2  = *(const float2*)(A   + (size_t)wid*DD + lane*2);
  const float2 wc  = *(const float2*)(ew1 + (size_t)512*DD + lane*2);
  const float2 bb1 = *(const float2*)(eb1 + lane*2);
  const float2 w2v = *(const float2*)(ew2 + lane*2);
  const float  b2s = eb2[0];
  const size_t e0 = (size_t)wid*KK;
  #pragma unroll
  for (int k=0;k<KK;k++){
    int dst = e_dst[e0+k];
    float val = e_val[e0+k];
    const float2 bv = *(const float2*)(Bv + ((size_t)b*NN+dst)*DD + lane*2);
    float h0 = a2.x + bv.x + val*wc.x + bb1.x;  h0 = h0>0.f ? h0 : expm1f(h0);
    float h1 = a2.y + bv.y + val*wc.y + bb1.y;  h1 = h1>0.f ? h1 : expm1f(h1);
    float s = h0*w2v.x + h1*w2v.y;
    #pragma unroll
    for (int off=32; off; off>>=1) s += __shfl_xor(s, off);
    if (lane==k) out_vals[e0+k] = 1.f/(1.f+expf(-(s+b2s)));
  }
}

// ---------------------------------------------------------------------------
extern "C" void kernel_launch(void* const* d_in, const int* in_sizes, int n_in,
                              void* d_out, int out_size, void* d_ws, size_t ws_size,
                              hipStream_t stream)
{
  const float* x    = (const float*)d_in[0];
  const float* ew1v = (const float*)d_in[1];
  const float* eb1v = (const float*)d_in[2];
  const float* ew2v = (const float*)d_in[3];
  const float* eb2v = (const float*)d_in[4];
  const float* gw1  = (const float*)d_in[5];
  const float* gb1  = (const float*)d_in[6];
  const float* gw2  = (const float*)d_in[7];
  const float* gb2  = (const float*)d_in[8];
  const float* rot  = (const float*)d_in[9];

  char* w = (char*)d_ws;
  float* pe   = (float*)w;  w += (size_t)BB*NN*DD*4;
  float* Atab = (float*)w;  w += (size_t)BB*NN*DD*4;
  float* Btab = (float*)w;  w += (size_t)BB*NN*DD*4;
  int*   bin_idx   = (int*)w; w += (size_t)BB*NN*4;
  int*   localrank = (int*)w; w += (size_t)BB*NN*4;
  int*   chunkhist = (int*)w; w += (size_t)BB*CHUNKS*NB*4;
  int*   bs        = (int*)w; w += (size_t)BB*NN*4;
  int*   e_dst     = (int*)w; w += (size_t)ETOT*4;
  float* e_val     = (float*)w; w += (size_t)ETOT*4;

  float* out_idx  = (float*)d_out;
  float* out_vals = out_idx + (size_t)ETOT*3;
  float* out_bins = out_vals + ETOT;

  k_fused<<<dim3(BB*CHUNKS), dim3(256), 0, stream>>>(
      x, ew1v, eb1v, ew2v, eb2v, rot, gw1,
      pe, Atab, Btab, bin_idx, localrank, chunkhist);
  k_scan_scatter<<<dim3(BB), dim3(256), 0, stream>>>(
      bin_idx, localrank, chunkhist, bs, out_bins);
  k_nn<<<dim3(BB*NB*8), dim3(256), 0, stream>>>(pe, bs, out_idx, e_dst, e_val);
  k_edge<<<dim3(BB*NN/4), dim3(256), 0, stream>>>(
      Atab, Btab, gw1, gb1, gw2, gb2, e_dst, e_val, out_vals);
}

// Round 5
// 503.116 us; speedup vs baseline: 1.3720x; 1.0224x over previous
//
#include <hip/hip_runtime.h>
#include <math.h>

#define BB 4
#define NN 8000
#define FIN 256
#define DD 128
#define NB 16
#define BS 500
#define KK 8
#define RPB 32
#define CHUNKS (NN/RPB)   /* 250 */
#define ETOT (BB*NN*KK)   /* 256000 */

// ---------------------------------------------------------------------------
// Kernel 1 (fused): encode FFN (256->128 elu->128) + LSH binning + edge tables
// Weight LDS rows use half-shift layout (elem j at j + 4*(j>=64)) so the
// 16-lane b128 reads are 2-way (free) instead of 4-way bank-conflicted.
// FMA order bit-identical to the verified round-3/4 version.
// ---------------------------------------------------------------------------
__global__ __launch_bounds__(256) void k_fused(
    const float* __restrict__ x, const float* __restrict__ w1, const float* __restrict__ b1,
    const float* __restrict__ w2, const float* __restrict__ b2, const float* __restrict__ rot,
    const float* __restrict__ ew1,
    float* __restrict__ pe, float* __restrict__ A, float* __restrict__ Bv,
    int* __restrict__ bin_idx, int* __restrict__ localrank, int* __restrict__ chunkhist)
{
  __shared__ float wsa[32*132];   // 16.9 KB
  __shared__ float wsb[32*132];   // 16.9 KB
  __shared__ float ps[RPB*132];   // 16.9 KB (h, then pe)
  __shared__ float ms[RPB*9];
  __shared__ int   bl[RPB];
  const int t = threadIdx.x;
  const int b = blockIdx.x / CHUNKS;
  const int chunk = blockIdx.x % CHUNKS;
  const int row0 = chunk * RPB;
  const int ri = t >> 4;            // 0..15 -> rows ri*2, ri*2+1
  const int ci = t & 15;            // 0..15 -> cols ci*8..+7
  const int r0t = ri*2, r1t = ri*2+1;
  const float* xrow0 = x + ((size_t)b*NN + row0 + r0t)*FIN;
  const float* xrow1 = x + ((size_t)b*NN + row0 + r1t)*FIN;
  const int sk = t >> 5, sc4 = t & 31;
  const int ss = (sc4>>4)<<2;       // staging half-shift
  const int cs = (ci>>3)<<2;        // read half-shift

  // ================= layer 1: K=256, 8 tiles =================
  float acc0[8], acc1[8];
  #pragma unroll
  for (int j=0;j<8;j++){ float bb = b1[ci*8+j]; acc0[j]=bb; acc1[j]=bb; }

  float4 rw0,rw1,rw2,rw3;
  { const float4* wg = (const float4*)w1;
    rw0=wg[t]; rw1=wg[t+256]; rw2=wg[t+512]; rw3=wg[t+768]; }
  int cur = 0;
  for (int kt=0; kt<8; ++kt){
    float* wsc = cur ? wsb : wsa;
    *(float4*)&wsc[(sk   )*132 + sc4*4 + ss] = rw0;
    *(float4*)&wsc[(sk+ 8)*132 + sc4*4 + ss] = rw1;
    *(float4*)&wsc[(sk+16)*132 + sc4*4 + ss] = rw2;
    *(float4*)&wsc[(sk+24)*132 + sc4*4 + ss] = rw3;
    if (kt<7){ const float4* wg = (const float4*)(w1 + (size_t)(kt+1)*32*DD);
      rw0=wg[t]; rw1=wg[t+256]; rw2=wg[t+512]; rw3=wg[t+768]; }
    __syncthreads();
    const float* xp0 = xrow0 + kt*32;
    const float* xp1 = xrow1 + kt*32;
    #pragma unroll
    for (int kc=0;kc<32;kc+=4){
      float4 a0 = *(const float4*)(xp0+kc);
      float4 a1 = *(const float4*)(xp1+kc);
      #pragma unroll
      for (int kk=0;kk<4;kk++){
        float4 wlo = *(const float4*)&wsc[(kc+kk)*132 + ci*8 + cs];
        float4 whi = *(const float4*)&wsc[(kc+kk)*132 + ci*8 + 4 + cs];
        float a0v = ((const float*)&a0)[kk], a1v = ((const float*)&a1)[kk];
        acc0[0]=fmaf(a0v,wlo.x,acc0[0]); acc0[1]=fmaf(a0v,wlo.y,acc0[1]);
        acc0[2]=fmaf(a0v,wlo.z,acc0[2]); acc0[3]=fmaf(a0v,wlo.w,acc0[3]);
        acc0[4]=fmaf(a0v,whi.x,acc0[4]); acc0[5]=fmaf(a0v,whi.y,acc0[5]);
        acc0[6]=fmaf(a0v,whi.z,acc0[6]); acc0[7]=fmaf(a0v,whi.w,acc0[7]);
        acc1[0]=fmaf(a1v,wlo.x,acc1[0]); acc1[1]=fmaf(a1v,wlo.y,acc1[1]);
        acc1[2]=fmaf(a1v,wlo.z,acc1[2]); acc1[3]=fmaf(a1v,wlo.w,acc1[3]);
        acc1[4]=fmaf(a1v,whi.x,acc1[4]); acc1[5]=fmaf(a1v,whi.y,acc1[5]);
        acc1[6]=fmaf(a1v,whi.z,acc1[6]); acc1[7]=fmaf(a1v,whi.w,acc1[7]);
      }
    }
    cur ^= 1;
  }
  // elu -> ps (h)
  #pragma unroll
  for (int j=0;j<8;j++){
    float v0=acc0[j]; ps[r0t*132 + ci*8 + j] = v0>0.f ? v0 : expm1f(v0);
    float v1=acc1[j]; ps[r1t*132 + ci*8 + j] = v1>0.f ? v1 : expm1f(v1);
  }

  // ================= layer 2: K=128, 4 tiles =================
  float acc20[8], acc21[8];
  #pragma unroll
  for (int j=0;j<8;j++){ float bb = b2[ci*8+j]; acc20[j]=bb; acc21[j]=bb; }
  { const float4* wg = (const float4*)w2;
    rw0=wg[t]; rw1=wg[t+256]; rw2=wg[t+512]; rw3=wg[t+768]; }
  for (int kt=0; kt<4; ++kt){
    float* wsc = cur ? wsb : wsa;
    *(float4*)&wsc[(sk   )*132 + sc4*4 + ss] = rw0;
    *(float4*)&wsc[(sk+ 8)*132 + sc4*4 + ss] = rw1;
    *(float4*)&wsc[(sk+16)*132 + sc4*4 + ss] = rw2;
    *(float4*)&wsc[(sk+24)*132 + sc4*4 + ss] = rw3;
    if (kt<3){ const float4* wg = (const float4*)(w2 + (size_t)(kt+1)*32*DD);
      rw0=wg[t]; rw1=wg[t+256]; rw2=wg[t+512]; rw3=wg[t+768]; }
    __syncthreads();   // ws ready; also makes ps (h) visible at kt==0
    #pragma unroll
    for (int kc=0;kc<32;kc+=4){
      float4 a0 = *(const float4*)&ps[r0t*132 + kt*32 + kc];
      float4 a1 = *(const float4*)&ps[r1t*132 + kt*32 + kc];
      #pragma unroll
      for (int kk=0;kk<4;kk++){
        float4 wlo = *(const float4*)&wsc[(kc+kk)*132 + ci*8 + cs];
        float4 whi = *(const float4*)&wsc[(kc+kk)*132 + ci*8 + 4 + cs];
        float a0v = ((const float*)&a0)[kk], a1v = ((const float*)&a1)[kk];
        acc20[0]=fmaf(a0v,wlo.x,acc20[0]); acc20[1]=fmaf(a0v,wlo.y,acc20[1]);
        acc20[2]=fmaf(a0v,wlo.z,acc20[2]); acc20[3]=fmaf(a0v,wlo.w,acc20[3]);
        acc20[4]=fmaf(a0v,whi.x,acc20[4]); acc20[5]=fmaf(a0v,whi.y,acc20[5]);
        acc20[6]=fmaf(a0v,whi.z,acc20[6]); acc20[7]=fmaf(a0v,whi.w,acc20[7]);
        acc21[0]=fmaf(a1v,wlo.x,acc21[0]); acc21[1]=fmaf(a1v,wlo.y,acc21[1]);
        acc21[2]=fmaf(a1v,wlo.z,acc21[2]); acc21[3]=fmaf(a1v,wlo.w,acc21[3]);
        acc21[4]=fmaf(a1v,whi.x,acc21[4]); acc21[5]=fmaf(a1v,whi.y,acc21[5]);
        acc21[6]=fmaf(a1v,whi.z,acc21[6]); acc21[7]=fmaf(a1v,whi.w,acc21[7]);
      }
    }
    cur ^= 1;
  }
  __syncthreads();   // all ps(h) readers done before overwrite with pe

  { float* pg0 = pe + ((size_t)b*NN + row0 + r0t)*DD + ci*8;
    float* pg1 = pe + ((size_t)b*NN + row0 + r1t)*DD + ci*8;
    #pragma unroll
    for (int j=0;j<8;j+=4){
      float4 v0 = make_float4(acc20[j],acc20[j+1],acc20[j+2],acc20[j+3]);
      float4 v1 = make_float4(acc21[j],acc21[j+1],acc21[j+2],acc21[j+3]);
      *(float4*)(pg0+j)=v0; *(float4*)&ps[r0t*132 + ci*8 + j]=v0;
      *(float4*)(pg1+j)=v1; *(float4*)&ps[r1t*132 + ci*8 + j]=v1;
    } }

  // ================= edge tables: K=256, 8 tiles, dual weights =============
  float aA0[8], aA1[8], aB0[8], aB1[8];
  #pragma unroll
  for (int j=0;j<8;j++){ aA0[j]=0.f; aA1[j]=0.f; aB0[j]=0.f; aB1[j]=0.f; }
  float4 ra0,ra1,ra2,ra3, rb0,rb1,rb2,rb3;
  { const float4* wga = (const float4*)ew1;
    const float4* wgb = (const float4*)(ew1 + (size_t)FIN*DD);
    ra0=wga[t]; ra1=wga[t+256]; ra2=wga[t+512]; ra3=wga[t+768];
    rb0=wgb[t]; rb1=wgb[t+256]; rb2=wgb[t+512]; rb3=wgb[t+768]; }
  for (int kt=0; kt<8; ++kt){
    __syncthreads();
    *(float4*)&wsa[(sk   )*132 + sc4*4 + ss] = ra0;
    *(float4*)&wsa[(sk+ 8)*132 + sc4*4 + ss] = ra1;
    *(float4*)&wsa[(sk+16)*132 + sc4*4 + ss] = ra2;
    *(float4*)&wsa[(sk+24)*132 + sc4*4 + ss] = ra3;
    *(float4*)&wsb[(sk   )*132 + sc4*4 + ss] = rb0;
    *(float4*)&wsb[(sk+ 8)*132 + sc4*4 + ss] = rb1;
    *(float4*)&wsb[(sk+16)*132 + sc4*4 + ss] = rb2;
    *(float4*)&wsb[(sk+24)*132 + sc4*4 + ss] = rb3;
    if (kt<7){
      const float4* wga = (const float4*)(ew1 + (size_t)(kt+1)*32*DD);
      const float4* wgb = (const float4*)(ew1 + (size_t)(FIN + (kt+1)*32)*DD);
      ra0=wga[t]; ra1=wga[t+256]; ra2=wga[t+512]; ra3=wga[t+768];
      rb0=wgb[t]; rb1=wgb[t+256]; rb2=wgb[t+512]; rb3=wgb[t+768]; }
    __syncthreads();
    const float* xp0 = xrow0 + kt*32;
    const float* xp1 = xrow1 + kt*32;
    #pragma unroll
    for (int kc=0;kc<32;kc+=4){
      float4 a0 = *(const float4*)(xp0+kc);
      float4 a1 = *(const float4*)(xp1+kc);
      #pragma unroll
      for (int kk=0;kk<4;kk++){
        float4 alo = *(const float4*)&wsa[(kc+kk)*132 + ci*8 + cs];
        float4 ahi = *(const float4*)&wsa[(kc+kk)*132 + ci*8 + 4 + cs];
        float4 blo = *(const float4*)&wsb[(kc+kk)*132 + ci*8 + cs];
        float4 bhi = *(const float4*)&wsb[(kc+kk)*132 + ci*8 + 4 + cs];
        float a0v = ((const float*)&a0)[kk], a1v = ((const float*)&a1)[kk];
        aA0[0]=fmaf(a0v,alo.x,aA0[0]); aA0[1]=fmaf(a0v,alo.y,aA0[1]);
        aA0[2]=fmaf(a0v,alo.z,aA0[2]); aA0[3]=fmaf(a0v,alo.w,aA0[3]);
        aA0[4]=fmaf(a0v,ahi.x,aA0[4]); aA0[5]=fmaf(a0v,ahi.y,aA0[5]);
        aA0[6]=fmaf(a0v,ahi.z,aA0[6]); aA0[7]=fmaf(a0v,ahi.w,aA0[7]);
        aA1[0]=fmaf(a1v,alo.x,aA1[0]); aA1[1]=fmaf(a1v,alo.y,aA1[1]);
        aA1[2]=fmaf(a1v,alo.z,aA1[2]); aA1[3]=fmaf(a1v,alo.w,aA1[3]);
        aA1[4]=fmaf(a1v,ahi.x,aA1[4]); aA1[5]=fmaf(a1v,ahi.y,aA1[5]);
        aA1[6]=fmaf(a1v,ahi.z,aA1[6]); aA1[7]=fmaf(a1v,ahi.w,aA1[7]);
        aB0[0]=fmaf(a0v,blo.x,aB0[0]); aB0[1]=fmaf(a0v,blo.y,aB0[1]);
        aB0[2]=fmaf(a0v,blo.z,aB0[2]); aB0[3]=fmaf(a0v,blo.w,aB0[3]);
        aB0[4]=fmaf(a0v,bhi.x,aB0[4]); aB0[5]=fmaf(a0v,bhi.y,aB0[5]);
        aB0[6]=fmaf(a0v,bhi.z,aB0[6]); aB0[7]=fmaf(a0v,bhi.w,aB0[7]);
        aB1[0]=fmaf(a1v,blo.x,aB1[0]); aB1[1]=fmaf(a1v,blo.y,aB1[1]);
        aB1[2]=fmaf(a1v,blo.z,aB1[2]); aB1[3]=fmaf(a1v,blo.w,aB1[3]);
        aB1[4]=fmaf(a1v,bhi.x,aB1[4]); aB1[5]=fmaf(a1v,bhi.y,aB1[5]);
        aB1[6]=fmaf(a1v,bhi.z,aB1[6]); aB1[7]=fmaf(a1v,bhi.w,aB1[7]);
      }
    }
  }
  { float* Ag0 = A  + ((size_t)b*NN+row0+r0t)*DD + ci*8;
    float* Ag1 = A  + ((size_t)b*NN+row0+r1t)*DD + ci*8;
    float* Bg0 = Bv + ((size_t)b*NN+row0+r0t)*DD + ci*8;
    float* Bg1 = Bv + ((size_t)b*NN+row0+r1t)*DD + ci*8;
    #pragma unroll
    for (int j=0;j<8;j+=4){
      *(float4*)(Ag0+j)=make_float4(aA0[j],aA0[j+1],aA0[j+2],aA0[j+3]);
      *(float4*)(Ag1+j)=make_float4(aA1[j],aA1[j+1],aA1[j+2],aA1[j+3]);
      *(float4*)(Bg0+j)=make_float4(aB0[j],aB0[j+1],aB0[j+2],aB0[j+3]);
      *(float4*)(Bg1+j)=make_float4(aB1[j],aB1[j+1],aB1[j+2],aB1[j+3]);
    } }

  // ================= LSH binning =================
  if (t<128){
    const int r = t>>2, m0 = t&3;
    float s0=0.f, s1=0.f;
    for (int k=0;k<DD;k++){
      float p = ps[r*132+k];
      s0 = fmaf(p, rot[k*100+m0],   s0);
      s1 = fmaf(p, rot[k*100+m0+4], s1);
    }
    ms[r*9+m0]=s0; ms[r*9+m0+4]=s1;
  }
  __syncthreads();
  if (t<RPB){
    float best = ms[t*9+0]; int bi=0;
    #pragma unroll
    for (int m=1;m<16;m++){
      float v = (m<8)? ms[t*9+m] : -ms[t*9+(m-8)];
      if (v>best){best=v;bi=m;}
    }
    bl[t]=bi;
    bin_idx[b*NN+row0+t]=bi;
  }
  __syncthreads();
  if (t<RPB){
    int myb=bl[t]; int rk=0;
    for (int r2=0;r2<t;r2++) rk += (bl[r2]==myb) ? 1 : 0;
    localrank[b*NN+row0+t]=rk;
  }
  if (t<NB){
    int cnt=0;
    #pragma unroll
    for (int r2=0;r2<RPB;r2++) cnt += (bl[r2]==t) ? 1 : 0;
    chunkhist[(b*CHUNKS+chunk)*NB + t] = cnt;
  }
}

// ---------------------------------------------------------------------------
// Kernel 2: fused parallel scan + stable scatter
// ---------------------------------------------------------------------------
__global__ __launch_bounds__(256) void k_scan_scatter(
    const int* __restrict__ bin_idx, const int* __restrict__ localrank,
    const int* __restrict__ chunkhist, int* __restrict__ bs, float* __restrict__ out_bins)
{
  const int b=blockIdx.x, t=threadIdx.x;
  __shared__ int cbase_s[CHUNKS*NB];
  __shared__ int segsum[16*NB];
  __shared__ int start[NB];
  const int m = t&15, s = t>>4;
  const int c0 = s*16, c1 = min(c0+16, CHUNKS);
  { int run=0;
    for (int c=c0;c<c1;c++) run += chunkhist[(b*CHUNKS+c)*NB+m];
    segsum[s*NB+m]=run; }
  __syncthreads();
  if (t<NB){
    int acc=0;
    for (int s2=0;s2<16;s2++){ int v=segsum[s2*NB+t]; segsum[s2*NB+t]=acc; acc+=v; }
    start[t]=acc;
  }
  __syncthreads();
  if (t==0){
    int run=0;
    for (int mm=0;mm<NB;mm++){ int tt=start[mm]; start[mm]=run; run+=tt; }
  }
  __syncthreads();
  { int acc = start[m] + segsum[s*NB+m];
    for (int c=c0;c<c1;c++){
      cbase_s[c*NB+m]=acc;
      acc += chunkhist[(b*CHUNKS+c)*NB+m];
    } }
  __syncthreads();
  for (int row=t; row<NN; row+=256){
    int gi=b*NN+row;
    int chunk=row>>5;
    int bi=bin_idx[gi];
    int pos=cbase_s[chunk*NB+bi]+localrank[gi];
    bs[b*NN+pos]=row;
    out_bins[b*NN+pos]=(float)row;
  }
}

// ---------------------------------------------------------------------------
// Kernel 3: per (batch, bin, 64-row tile) pairwise gaussian + top-8.
// BARRIER-FREE main loop: each wave owns a private 16-col LDS slice and
// walks its 8 subtiles (st = 4q+w) with reg-prefetch (T14). RT shared,
// read-only, per-row XOR swizzle. Math bit-identical to round 4.
// ---------------------------------------------------------------------------
__global__ __launch_bounds__(256) void k_nn(
    const float* __restrict__ pe, const int* __restrict__ bs,
    float* __restrict__ out_idx, int* __restrict__ e_dst, float* __restrict__ e_val)
{
  __shared__ float RT[64*132];     // 33.8 KB row tile (later merge vals [128][65])
  __shared__ float CT[4*16*132];   // 33.8 KB 4 wave-private 16-col slices (later merge idx)
  __shared__ float na_all[512];
  __shared__ int   bsl[BS];
  const int t=threadIdx.x;
  const int blk=blockIdx.x;                 // b*128 + bin*8 + rt
  const int rt=blk&7, bin=(blk>>3)&15, b=blk>>7;
  const int w = t>>6, lane = t&63;
  const int tr = lane>>2, tc = lane&3;      // thread tile: rows tr*4..+3, cols tc*4..+3
  const float* peb = pe + (size_t)b*NN*DD;

  for (int i=t;i<BS;i+=256) bsl[i]=bs[b*NN + bin*BS + i];
  __syncthreads();

  // squared norms (same sequential accumulation as verified version)
  for (int i=t;i<512;i+=256){
    float s=0.f;
    if (i<BS){
      const float* pr = peb + (size_t)bsl[i]*DD;
      for (int k=0;k<DD;k+=4){
        float4 v=*(const float4*)(pr+k);
        s=fmaf(v.x,v.x,s); s=fmaf(v.y,v.y,s); s=fmaf(v.z,v.z,s); s=fmaf(v.w,v.w,s);
      }
    }
    na_all[i]=s;
  }

  const int r0=rt*64;
  const int nr=min(64, BS-r0);              // 64 or 52
  { const int lr=t>>5, c4=t&31;
    #pragma unroll
    for (int pass=0;pass<8;pass++){
      int r=pass*8+lr;
      float4 v=make_float4(0.f,0.f,0.f,0.f);
      if (r<nr) v=*(const float4*)(peb + (size_t)bsl[r0+r]*DD + c4*4);
      *(float4*)&RT[r*132 + ((c4*4) ^ (((r>>2)&7)<<2))] = v;
    } }

  // issue CT loads for this wave's first subtile (st = w; cols < 64 < BS)
  const int scol = lane>>2, sch = lane&3;   // staging: col 0..15, chunk 0..3
  float* ctw = CT + w*(16*132);
  float4 creg[8];
  { const float* src = peb + (size_t)bsl[w*16 + scol]*DD;
    #pragma unroll
    for (int p=0;p<8;p++) creg[p]=*(const float4*)(src + (sch+4*p)*4);
  }
  __syncthreads();      // RT + na + bsl visible to all

  #pragma unroll
  for (int p=0;p<8;p++)
    *(float4*)&ctw[scol*132 + (sch+4*p)*4] = creg[p];

  float tv[4][8]; int tix[4][8];
  #pragma unroll
  for (int i=0;i<4;i++){
    #pragma unroll
    for (int s=0;s<8;s++){ tv[i][s]=-1e30f; tix[i][s]=0; } }

  const int aswz = (tr&7)<<2;

  for (int q=0;q<8;q++){
    const int c0 = (4*q + w)*16;
    // prefetch next subtile (st+4) into regs; hides under GEMM
    if (q<7){
      int cn = c0 + 64 + scol;
      const float* src = peb + (size_t)bsl[(cn<BS)?cn:0]*DD;
      #pragma unroll
      for (int p=0;p<8;p++){
        float4 v=*(const float4*)(src + (sch+4*p)*4);
        creg[p] = (cn<BS) ? v : make_float4(0.f,0.f,0.f,0.f);
      }
    }

    float accm[4][4];
    #pragma unroll
    for (int i=0;i<4;i++){
      #pragma unroll
      for (int j=0;j<4;j++) accm[i][j]=0.f; }
    #pragma unroll 8
    for (int k0=0;k0<DD;k0+=4){
      float4 a4[4], b4[4];
      #pragma unroll
      for (int i=0;i<4;i++) a4[i]=*(const float4*)&RT[(tr*4+i)*132 + (k0 ^ aswz)];
      #pragma unroll
      for (int j=0;j<4;j++) b4[j]=*(const float4*)&ctw[(tc*4+j)*132 + k0];
      #pragma unroll
      for (int kk=0;kk<4;kk++){
        #pragma unroll
        for (int i=0;i<4;i++){
          float av=((const float*)&a4[i])[kk];
          #pragma unroll
          for (int j=0;j<4;j++){
            float bvv=((const float*)&b4[j])[kk];
            accm[i][j]=fmaf(av,bvv,accm[i][j]);
          }
        }
      }
    }

    float nrow[4], ncol[4];
    #pragma unroll
    for (int i=0;i<4;i++) nrow[i]=na_all[r0+tr*4+i];
    #pragma unroll
    for (int j=0;j<4;j++) ncol[j]=na_all[c0+tc*4+j];

    #pragma unroll
    for (int i=0;i<4;i++){
      #pragma unroll
      for (int j=0;j<4;j++){
        float t1=nrow[i]-2.f*accm[i][j];
        float d2v=t1+ncol[j];
        float dm=expf(-0.1f*sqrtf(fmaxf(d2v,1e-6f)));
        int c=c0+tc*4+j;
        if (c<BS && dm>tv[i][7]){          // strict > : lax.top_k tie semantics
          tv[i][7]=dm; tix[i][7]=c;
          #pragma unroll
          for (int qq=7;qq>0;qq--){
            if (tv[i][qq]>tv[i][qq-1]){
              float tf=tv[i][qq];tv[i][qq]=tv[i][qq-1];tv[i][qq-1]=tf;
              int   td=tix[i][qq];tix[i][qq]=tix[i][qq-1];tix[i][qq-1]=td;
            }
          }
        }
      }
    }

    // write prefetched slice (within-wave ordering only; no barrier)
    if (q<7){
      #pragma unroll
      for (int p=0;p<8;p++)
        *(float4*)&ctw[scol*132 + (sch+4*p)*4] = creg[p];
    }
  }

  __syncthreads();     // all waves done with RT/CT before reuse as scratch
  // dump partials transposed: p = (w*4+tc)*8+s; vals in RT, idx in CT
  #pragma unroll
  for (int i=0;i<4;i++){
    const int row=tr*4+i;
    #pragma unroll
    for (int s=0;s<8;s++){
      const int p=(w*4+tc)*8+s;
      RT[p*65 + row]=tv[i][s];
      CT[p*65 + row]=__int_as_float(tix[i][s]);
    }
  }
  __syncthreads();

  if (t<nr){
    float mv[8]; int mi[8];
    #pragma unroll
    for (int s=0;s<8;s++){ mv[s]=-1e30f; mi[s]=0; }
    #pragma unroll 4
    for (int p=0;p<128;p++){
      float v=RT[p*65+t]; int c=__float_as_int(CT[p*65+t]);
      if (v>mv[7] || (v==mv[7] && c<mi[7])){
        mv[7]=v; mi[7]=c;
        #pragma unroll
        for (int qq=7;qq>0;qq--){
          bool sw=(mv[qq]>mv[qq-1]) || (mv[qq]==mv[qq-1] && mi[qq]<mi[qq-1]);
          if (sw){
            float tf=mv[qq];mv[qq]=mv[qq-1];mv[qq-1]=tf;
            int   td=mi[qq];mi[qq]=mi[qq-1];mi[qq-1]=td;
          }
        }
      }
    }
    const int src=bsl[r0+t];
    int dsts[KK]; float vv[KK];
    #pragma unroll
    for (int k2=0;k2<KK;k2++){ dsts[k2]=bsl[mi[k2]]; vv[k2]=mv[k2]; }
    #define CSWAP(a_,b_) { if (dsts[a_]>dsts[b_]){ int td=dsts[a_];dsts[a_]=dsts[b_];dsts[b_]=td; float tf=vv[a_];vv[a_]=vv[b_];vv[b_]=tf; } }
    CSWAP(0,1) CSWAP(2,3) CSWAP(4,5) CSWAP(6,7)
    CSWAP(0,2) CSWAP(1,3) CSWAP(4,6) CSWAP(5,7)
    CSWAP(1,2) CSWAP(5,6)
    CSWAP(0,4) CSWAP(1,5) CSWAP(2,6) CSWAP(3,7)
    CSWAP(2,4) CSWAP(3,5)
    CSWAP(1,2) CSWAP(3,4) CSWAP(5,6)
    #undef CSWAP
    size_t e0=((size_t)b*NN + src)*KK;
    #pragma unroll
    for (int k2=0;k2<KK;k2++){
      out_idx[3*(e0+k2)+0]=(float)b;
      out_idx[3*(e0+k2)+1]=(float)src;
      out_idx[3*(e0+k2)+2]=(float)dsts[k2];
      e_dst[e0+k2]=dsts[k2];
      e_val[e0+k2]=vv[k2];
    }
  }
}

// ---------------------------------------------------------------------------
// Kernel 4: edge MLP. One wave per (b,src) group of 8 edges.
// ---------------------------------------------------------------------------
__global__ __launch_bounds__(256) void k_edge(
    const float* __restrict__ A, const float* __restrict__ Bv,
    const float* __restrict__ ew1, const float* __restrict__ eb1,
    const float* __restrict__ ew2, const float* __restrict__ eb2,
    const int* __restrict__ e_dst, const float* __restrict__ e_val,
    float* __restrict__ out_vals)
{
  const int wid = (int)((blockIdx.x*256u+threadIdx.x)>>6);
  const int lane = threadIdx.x&63;
  if (wid >= BB*NN) return;
  const int b = wid / NN;
  const float2 a2  = *(const float2*)(A   + (size_t)wid*DD + lane*2);
  const float2 wc  = *(const float2*)(ew1 + (size_t)512*DD + lane*2);
  const float2 bb1 = *(const float2*)(eb1 + lane*2);
  const float2 w2v = *(const float2*)(ew2 + lane*2);
  const float  b2s = eb2[0];
  const size_t e0 = (size_t)wid*KK;
  #pragma unroll
  for (int k=0;k<KK;k++){
    int dst = e_dst[e0+k];
    float val = e_val[e0+k];
    const float2 bv = *(const float2*)(Bv + ((size_t)b*NN+dst)*DD + lane*2);
    float h0 = a2.x + bv.x + val*wc.x + bb1.x;  h0 = h0>0.f ? h0 : expm1f(h0);
    float h1 = a2.y + bv.y + val*wc.y + bb1.y;  h1 = h1>0.f ? h1 : expm1f(h1);
    float s = h0*w2v.x + h1*w2v.y;
    #pragma unroll
    for (int off=32; off; off>>=1) s += __shfl_xor(s, off);
    if (lane==k) out_vals[e0+k] = 1.f/(1.f+expf(-(s+b2s)));
  }
}

// ---------------------------------------------------------------------------
extern "C" void kernel_launch(void* const* d_in, const int* in_sizes, int n_in,
                              void* d_out, int out_size, void* d_ws, size_t ws_size,
                              hipStream_t stream)
{
  const float* x    = (const float*)d_in[0];
  const float* ew1v = (const float*)d_in[1];
  const float* eb1v = (const float*)d_in[2];
  const float* ew2v = (const float*)d_in[3];
  const float* eb2v = (const float*)d_in[4];
  const float* gw1  = (const float*)d_in[5];
  const float* gb1  = (const float*)d_in[6];
  const float* gw2  = (const float*)d_in[7];
  const float* gb2  = (const float*)d_in[8];
  const float* rot  = (const float*)d_in[9];

  char* w = (char*)d_ws;
  float* pe   = (float*)w;  w += (size_t)BB*NN*DD*4;
  float* Atab = (float*)w;  w += (size_t)BB*NN*DD*4;
  float* Btab = (float*)w;  w += (size_t)BB*NN*DD*4;
  int*   bin_idx   = (int*)w; w += (size_t)BB*NN*4;
  int*   localrank = (int*)w; w += (size_t)BB*NN*4;
  int*   chunkhist = (int*)w; w += (size_t)BB*CHUNKS*NB*4;
  int*   bs        = (int*)w; w += (size_t)BB*NN*4;
  int*   e_dst     = (int*)w; w += (size_t)ETOT*4;
  float* e_val     = (float*)w; w += (size_t)ETOT*4;

  float* out_idx  = (float*)d_out;
  float* out_vals = out_idx + (size_t)ETOT*3;
  float* out_bins = out_vals + ETOT;

  k_fused<<<dim3(BB*CHUNKS), dim3(256), 0, stream>>>(
      x, ew1v, eb1v, ew2v, eb2v, rot, gw1,
      pe, Atab, Btab, bin_idx, localrank, chunkhist);
  k_scan_scatter<<<dim3(BB), dim3(256), 0, stream>>>(
      bin_idx, localrank, chunkhist, bs, out_bins);
  k_nn<<<dim3(BB*NB*8), dim3(256), 0, stream>>>(pe, bs, out_idx, e_dst, e_val);
  k_edge<<<dim3(BB*NN/4), dim3(256), 0, stream>>>(
      Atab, Btab, gw1, gb1, gw2, gb2, e_dst, e_val, out_vals);
}